// Round 2
// baseline (2035.246 us; speedup 1.0000x reference)
//
#include <hip/hip_runtime.h>
#include <stdint.h>
#include <stddef.h>

constexpr int IMH = 192;
constexpr int IMW = 192;
constexpr int HW  = 36864;   // 192*192
constexpr int BB  = 2;
constexpr int CC  = 64;
constexpr int CHF = 32;      // half channels (sorted part)
constexpr int C5  = 320;     // 5*CC
constexpr int NQ  = 9216;    // HW/4
constexpr int CROWS = 64;    // fuse-pipeline chunk rows
constexpr int CHWN  = CROWS * IMW;  // 12288 cols per chunk

// ---------- float <-> monotone uint32 (order-preserving, invertible) ----------
static __device__ __forceinline__ uint32_t f2s(float f) {
    uint32_t u = __float_as_uint(f);
    return (u & 0x80000000u) ? ~u : (u | 0x80000000u);
}
static __device__ __forceinline__ float s2f(uint32_t s) {
    uint32_t u = (s & 0x80000000u) ? (s & 0x7FFFFFFFu) : ~s;
    return __uint_as_float(u);
}

// ---------- bitonic sort of 256 u64 keys in LDS (128 threads) ----------
static __device__ void bitonic256(uint64_t* keys, int tid) {
    for (unsigned k = 2; k <= 256; k <<= 1) {
        for (unsigned j = k >> 1; j; j >>= 1) {
            __syncthreads();
            unsigned i = ((tid & ~(j - 1)) << 1) | (tid & (j - 1));
            unsigned p = i | j;
            bool up = ((i & k) == 0);
            uint64_t a = keys[i], b = keys[p];
            if ((a > b) == up) { keys[i] = b; keys[p] = a; }
        }
    }
    __syncthreads();
}

// ---------- K0: copy unsorted half channels into A ----------
__global__ void k_copy_back(const float* __restrict__ x, float* __restrict__ A) {
    int i = blockIdx.x * 256 + threadIdx.x;        // over BB*CHF*HW
    int b = i / (CHF * HW);
    int r = i % (CHF * HW);
    size_t o = ((size_t)(b * CC) + CHF) * HW + r;
    A[o] = x[o];
}

// ---------- K1: stable sort along H (per b,c,w column), write A + idx_h ----------
__global__ __launch_bounds__(128) void k_sort_h(const float* __restrict__ x, float* __restrict__ A,
                                                int* __restrict__ idx_h) {
    __shared__ uint64_t keys[256];
    int tid = threadIdx.x;
    int blk = blockIdx.x;
    int w = blk % IMW;
    int c = (blk / IMW) % CHF;
    int b = blk / (IMW * CHF);
    const float* col = x + ((size_t)(b * CC) + c) * HW + w;
    for (int i = tid; i < 256; i += 128)
        keys[i] = (i < IMH) ? ((((uint64_t)f2s(col[(size_t)i * IMW])) << 32) | (uint32_t)i) : ~0ull;
    bitonic256(keys, tid);
    float* ocol = A + ((size_t)(b * CC) + c) * HW + w;
    int* icol = idx_h + ((size_t)(b * CHF) + c) * HW + w;
    for (int i = tid; i < IMH; i += 128) {
        uint64_t k = keys[i];
        ocol[(size_t)i * IMW] = s2f((uint32_t)(k >> 32));
        icol[(size_t)i * IMW] = (int)(k & 0xFFFFFFFFull);
    }
}

// ---------- K2: stable sort along W (per b,c,h row), in-place on A, write idx_w ----------
__global__ __launch_bounds__(128) void k_sort_w(float* __restrict__ A, int* __restrict__ idx_w) {
    __shared__ uint64_t keys[256];
    int tid = threadIdx.x;
    int blk = blockIdx.x;
    int h = blk % IMH;
    int c = (blk / IMH) % CHF;
    int b = blk / (IMH * CHF);
    float* row = A + ((size_t)(b * CC) + c) * HW + (size_t)h * IMW;
    for (int i = tid; i < 256; i += 128)
        keys[i] = (i < IMW) ? ((((uint64_t)f2s(row[i])) << 32) | (uint32_t)i) : ~0ull;
    bitonic256(keys, tid);
    int* irow = idx_w + ((size_t)(b * CHF) + c) * HW + (size_t)h * IMW;
    for (int i = tid; i < IMW; i += 128) {
        uint64_t k = keys[i];
        row[i] = s2f((uint32_t)(k >> 32));
        irow[i] = (int)(k & 0xFFFFFFFFull);
    }
}

// ---------- K3: q = W_qkv(320x64) * A(64xHW) per batch ----------
__global__ __launch_bounds__(256) void k_gemm_q(const float* __restrict__ wq, const float* __restrict__ A,
                                                float* __restrict__ q) {
    __shared__ float Wt[64][68];
    __shared__ float Xt[64][68];
    int tid = threadIdx.x;
    int n0 = blockIdx.x * 64, m0 = blockIdx.y * 64, b = blockIdx.z;
    for (int l = 0; l < 16; ++l) {
        int idx = l * 256 + tid;
        int cc = idx & 63, m = idx >> 6;
        Wt[cc][m] = wq[(size_t)(m0 + m) * 64 + cc];
    }
    for (int l = 0; l < 16; ++l) {
        int idx = l * 256 + tid;
        int n = idx & 63, cc = idx >> 6;
        Xt[cc][n] = A[((size_t)(b * CC) + cc) * HW + n0 + n];
    }
    __syncthreads();
    int ty = tid >> 4, tx = tid & 15;
    float acc[4][4] = {};
    for (int cc = 0; cc < 64; ++cc) {
        float4 av = *(const float4*)&Wt[cc][ty * 4];
        float4 bv = *(const float4*)&Xt[cc][tx * 4];
        float aa[4] = {av.x, av.y, av.z, av.w};
        float bb[4] = {bv.x, bv.y, bv.z, bv.w};
        #pragma unroll
        for (int i = 0; i < 4; ++i)
            #pragma unroll
            for (int j = 0; j < 4; ++j)
                acc[i][j] = fmaf(aa[i], bb[j], acc[i][j]);
    }
    for (int i = 0; i < 4; ++i) {
        float4 o;
        o.x = acc[i][0]; o.y = acc[i][1]; o.z = acc[i][2]; o.w = acc[i][3];
        *(float4*)&q[((size_t)(b * C5) + m0 + ty * 4 + i) * HW + n0 + tx * 4] = o;
    }
}

// ---------- K4: depthwise conv KSxKS (zero pad) for a 64-row chunk starting at r0 ----------
// slice chunk layout: [b][c][CROWS*IMW]
template <int KS>
__global__ __launch_bounds__(256) void k_dwconv(const float* __restrict__ q, const float* __restrict__ wd,
                                                float* __restrict__ slice, int r0) {
    constexpr int PAD = KS / 2;
    constexpr int EXT = 32 + 2 * PAD;
    __shared__ float tile[EXT][EXT];
    int tid = threadIdx.x;
    int b = blockIdx.z, c = blockIdx.y;
    int t = blockIdx.x;                  // 12 tiles: 2 tile-rows x 6 tile-cols
    int ty0 = r0 + (t / 6) * 32, tx0 = (t % 6) * 32;
    const float* src = q + ((size_t)(b * C5) + c) * HW;
    for (int i = tid; i < EXT * EXT; i += 256) {
        int iy = i / EXT, ix = i % EXT;
        int gy = ty0 + iy - PAD, gx = tx0 + ix - PAD;
        float v = 0.f;
        if (gy >= 0 && gy < IMH && gx >= 0 && gx < IMW) v = src[gy * IMW + gx];
        tile[iy][ix] = v;
    }
    __syncthreads();
    float wreg[KS * KS];
    #pragma unroll
    for (int i = 0; i < KS * KS; ++i) wreg[i] = wd[(size_t)c * KS * KS + i];
    float* dst = slice + ((size_t)(b * C5) + c) * CHWN;
    #pragma unroll
    for (int k = 0; k < 4; ++k) {
        int pix = k * 256 + tid;
        int py = pix >> 5, px = pix & 31;
        float acc = 0.f;
        #pragma unroll
        for (int ky = 0; ky < KS; ++ky)
            #pragma unroll
            for (int kx = 0; kx < KS; ++kx)
                acc = fmaf(tile[py + ky][px + kx], wreg[ky * KS + kx], acc);
        dst[(ty0 - r0 + py) * IMW + tx0 + px] = acc;
    }
}

// ---------- K5: qkv(chunk) (+)= W_fuse[:, g*320:(g+1)*320] * slice(chunk) ; g==0 writes + bias ----------
__global__ __launch_bounds__(256) void k_gemm_fuse(const float* __restrict__ wf, const float* __restrict__ slice,
                                                   const float* __restrict__ bias, float* __restrict__ qkv,
                                                   int g, int r0) {
    __shared__ float Wt[8][68];
    __shared__ float Xt[8][132];
    int tid = threadIdx.x;
    int n0 = blockIdx.x * 128, m0 = blockIdx.y * 64, b = blockIdx.z;
    int gk = g * 320;
    int ty = tid >> 4, tx = tid & 15;
    float acc[4][8] = {};
    for (int k0 = 0; k0 < 320; k0 += 8) {
        __syncthreads();
        #pragma unroll
        for (int l = 0; l < 2; ++l) {
            int id2 = l * 256 + tid;
            int m = id2 >> 3, kk = id2 & 7;
            Wt[kk][m] = wf[(size_t)(m0 + m) * 960 + gk + k0 + kk];
        }
        #pragma unroll
        for (int l = 0; l < 4; ++l) {
            int id2 = l * 256 + tid;
            int n = id2 & 127, kk = id2 >> 7;
            Xt[kk][n] = slice[((size_t)(b * C5) + k0 + kk) * CHWN + n0 + n];
        }
        __syncthreads();
        #pragma unroll
        for (int kk = 0; kk < 8; ++kk) {
            float4 av = *(const float4*)&Wt[kk][ty * 4];
            float4 b0 = *(const float4*)&Xt[kk][tx * 8];
            float4 b1 = *(const float4*)&Xt[kk][tx * 8 + 4];
            float aa[4] = {av.x, av.y, av.z, av.w};
            float bb[8] = {b0.x, b0.y, b0.z, b0.w, b1.x, b1.y, b1.z, b1.w};
            #pragma unroll
            for (int i = 0; i < 4; ++i)
                #pragma unroll
                for (int j = 0; j < 8; ++j)
                    acc[i][j] = fmaf(aa[i], bb[j], acc[i][j]);
        }
    }
    for (int i = 0; i < 4; ++i) {
        int m = m0 + ty * 4 + i;
        size_t base = ((size_t)(b * C5) + m) * HW + (size_t)r0 * IMW + n0 + tx * 8;
        if (g == 0) {
            float bv = bias[m];
            for (int j = 0; j < 8; ++j) qkv[base + j] = acc[i][j] + bv;
        } else {
            for (int j = 0; j < 8; ++j) qkv[base + j] += acc[i][j];
        }
    }
}

// ---------- K6a: build (value || index) u64 keys for v rows ----------
__global__ void k_build_keys(const float* __restrict__ qkv, uint64_t* __restrict__ keyA) {
    int j = blockIdx.x * 256 + threadIdx.x;
    int row = blockIdx.y;               // b*64+c
    int b = row >> 6, c = row & 63;
    float v = qkv[((size_t)(b * C5) + 256 + c) * HW + j];
    keyA[(size_t)row * HW + j] = (((uint64_t)f2s(v)) << 32) | (uint32_t)j;
}

// ---------- K6b: one stable LSD radix pass (6-bit digit), one block per row ----------
__global__ __launch_bounds__(256) void k_radix_pass(const uint64_t* __restrict__ in, uint64_t* __restrict__ out,
                                                    int shift) {
    __shared__ uint16_t cnt[256][66];
    __shared__ uint32_t base[64];
    int t = threadIdx.x;
    int row = blockIdx.x;
    const uint64_t* src = in + (size_t)row * HW;
    uint64_t* dst = out + (size_t)row * HW;
    for (int d = 0; d < 66; ++d) cnt[t][d] = 0;
    __syncthreads();
    const int CHUNK = HW / 256;  // 144
    int s0 = t * CHUNK;
    for (int i = 0; i < CHUNK; ++i) {
        unsigned d = (unsigned)(src[s0 + i] >> shift) & 63u;
        cnt[t][d] = (uint16_t)(cnt[t][d] + 1);
    }
    __syncthreads();
    if (t < 64) {
        uint32_t s = 0;
        for (int tt = 0; tt < 256; ++tt) {
            uint32_t cv = cnt[tt][t];
            cnt[tt][t] = (uint16_t)s;
            s += cv;
        }
        base[t] = s;
    }
    __syncthreads();
    if (t == 0) {
        uint32_t s = 0;
        for (int d = 0; d < 64; ++d) { uint32_t cv = base[d]; base[d] = s; s += cv; }
    }
    __syncthreads();
    for (int i = 0; i < CHUNK; ++i) {
        uint64_t k = src[s0 + i];
        unsigned d = (unsigned)(k >> shift) & 63u;
        uint32_t pos = base[d] + cnt[t][d];
        cnt[t][d] = (uint16_t)(cnt[t][d] + 1);
        dst[pos] = k;
    }
}

// ---------- K6c: unpack sorted keys -> vs, idxv ----------
__global__ void k_unpack(const uint64_t* __restrict__ keys, float* __restrict__ vs, int* __restrict__ idxv) {
    int j = blockIdx.x * 256 + threadIdx.x;
    int row = blockIdx.y;
    size_t o = (size_t)row * HW + j;
    uint64_t k = keys[o];
    vs[o] = s2f((uint32_t)(k >> 32));
    idxv[o] = (int)(k & 0xFFFFFFFFull);
}

// ---------- K7a: raw S = Q*K^T partials + norm^2 partials; gathers q/k from qkv via idxv ----------
__global__ __launch_bounds__(256) void k_attn_qk(const float* __restrict__ qkv, const int* __restrict__ idxv,
                                                 float* __restrict__ partS, float* __restrict__ partN) {
    __shared__ float Qs[16][68];
    __shared__ float Ks[16][68];
    __shared__ float nqs[4][64];
    __shared__ float nks[4][64];
    int tid = threadIdx.x;
    int ychunk = blockIdx.x;   // 16 chunks of 576
    int z = blockIdx.y;        // 16 = b(2) x h(4) x variant(2)
    int vi = z & 1, hh = (z >> 1) & 3, b = z >> 3;
    int qoff = vi ? 128 : 0, koff = vi ? 192 : 64;
    int ty = tid >> 4, tx = tid & 15;
    float acc[4][4] = {};
    float nq = 0.f, nk = 0.f;
    int d0 = tid & 63, kset = tid >> 6;
    int nbase0 = ychunk * 576;
    for (int it = 0; it < 36; ++it) {
        int nb0 = nbase0 + it * 16;
        __syncthreads();
        #pragma unroll
        for (int l = 0; l < 4; ++l) {
            int idx = l * 256 + tid;
            int d = idx >> 4, kk = idx & 15;
            int n = nb0 + kk;
            int cch = hh * 16 + (d >> 2), f = d & 3;
            int srcpos = vi ? (n * 4 + f) : (f * NQ + n);
            int p = idxv[((size_t)(b * CC) + cch) * HW + srcpos];
            Qs[kk][d] = qkv[((size_t)(b * C5) + qoff + cch) * HW + p];
            Ks[kk][d] = qkv[((size_t)(b * C5) + koff + cch) * HW + p];
        }
        __syncthreads();
        #pragma unroll
        for (int kk = 0; kk < 16; ++kk) {
            float4 av = *(const float4*)&Qs[kk][ty * 4];
            float4 bv = *(const float4*)&Ks[kk][tx * 4];
            float aa[4] = {av.x, av.y, av.z, av.w};
            float bb[4] = {bv.x, bv.y, bv.z, bv.w};
            #pragma unroll
            for (int i = 0; i < 4; ++i)
                #pragma unroll
                for (int j = 0; j < 4; ++j)
                    acc[i][j] = fmaf(aa[i], bb[j], acc[i][j]);
        }
        #pragma unroll
        for (int kk2 = 0; kk2 < 4; ++kk2) {
            float qv = Qs[kset * 4 + kk2][d0];
            float kv = Ks[kset * 4 + kk2][d0];
            nq = fmaf(qv, qv, nq);
            nk = fmaf(kv, kv, nk);
        }
    }
    size_t sb = ((size_t)z * 16 + ychunk) * 4096;
    #pragma unroll
    for (int i = 0; i < 4; ++i)
        #pragma unroll
        for (int j = 0; j < 4; ++j)
            partS[sb + (size_t)(ty * 4 + i) * 64 + tx * 4 + j] = acc[i][j];
    nqs[kset][d0] = nq;
    nks[kset][d0] = nk;
    __syncthreads();
    if (tid < 64) {
        float sq = nqs[0][tid] + nqs[1][tid] + nqs[2][tid] + nqs[3][tid];
        float sk = nks[0][tid] + nks[1][tid] + nks[2][tid] + nks[3][tid];
        size_t nb2 = ((size_t)z * 16 + ychunk) * 128;
        partN[nb2 + tid] = sq;
        partN[nb2 + 64 + tid] = sk;
    }
}

// ---------- K7b: reduce partials, normalize, exp, denom = rowsum+1 ; write attn^T ----------
__global__ __launch_bounds__(256) void k_attn_softmax(const float* __restrict__ partS,
                                                      const float* __restrict__ partN,
                                                      const float* __restrict__ temp, float* __restrict__ attnT) {
    __shared__ float nqv[64], nkv[64];
    __shared__ float pbuf[64][65];
    __shared__ float rred[64][4];
    __shared__ float rsum[64];
    int tid = threadIdx.x;
    int z = blockIdx.x;
    int hh = (z >> 1) & 3;
    if (tid < 128) {
        float s = 0.f;
        for (int ch = 0; ch < 16; ++ch) s += partN[((size_t)z * 16 + ch) * 128 + tid];
        float nv = fmaxf(sqrtf(s), 1e-12f);
        if (tid < 64) nqv[tid] = nv; else nkv[tid - 64] = nv;
    }
    __syncthreads();
    float tf = temp[hh];
    int d = tid >> 2, qq = tid & 3;
    float psum = 0.f;
    for (int e = qq * 16; e < qq * 16 + 16; ++e) {
        float s = 0.f;
        for (int ch = 0; ch < 16; ++ch) s += partS[((size_t)z * 16 + ch) * 4096 + (size_t)d * 64 + e];
        float p = expf(tf * s / (nqv[d] * nkv[e]));
        pbuf[d][e] = p;
        psum += p;
    }
    rred[d][qq] = psum;
    __syncthreads();
    if (tid < 64) rsum[tid] = rred[tid][0] + rred[tid][1] + rred[tid][2] + rred[tid][3] + 1.0f;
    __syncthreads();
    for (int e = qq * 16; e < qq * 16 + 16; ++e)
        attnT[(size_t)z * 4096 + (size_t)e * 64 + d] = pbuf[d][e] / rsum[d];
}

// ---------- K7c: O = attn * V, written back to (c, sorted-position) layout ----------
__global__ __launch_bounds__(256) void k_attn_av(const float* __restrict__ attnT, const float* __restrict__ vs,
                                                 float* __restrict__ O1, float* __restrict__ O2) {
    __shared__ float at_s[4096];
    int tid = threadIdx.x;
    int z = blockIdx.y;
    int vi = z & 1, hh = (z >> 1) & 3, b = z >> 3;
    for (int l = 0; l < 16; ++l) at_s[l * 256 + tid] = attnT[(size_t)z * 4096 + l * 256 + tid];
    __syncthreads();
    int n = blockIdx.x * 256 + tid;
    float acc[64];
    #pragma unroll
    for (int d = 0; d < 64; ++d) acc[d] = 0.f;
    for (int e = 0; e < 64; ++e) {
        int cch = hh * 16 + (e >> 2), f = e & 3;
        size_t p = vi ? (size_t)(n * 4 + f) : (size_t)(f * NQ + n);
        float vv = vs[((size_t)(b * CC) + cch) * HW + p];
        const float* ar = &at_s[e * 64];
        #pragma unroll
        for (int d4 = 0; d4 < 16; ++d4) {
            float4 a4 = *(const float4*)&ar[d4 * 4];
            acc[d4 * 4 + 0] = fmaf(a4.x, vv, acc[d4 * 4 + 0]);
            acc[d4 * 4 + 1] = fmaf(a4.y, vv, acc[d4 * 4 + 1]);
            acc[d4 * 4 + 2] = fmaf(a4.z, vv, acc[d4 * 4 + 2]);
            acc[d4 * 4 + 3] = fmaf(a4.w, vv, acc[d4 * 4 + 3]);
        }
    }
    float* Ob = vi ? O2 : O1;
    #pragma unroll
    for (int d = 0; d < 64; ++d) {
        int cch = hh * 16 + (d >> 2), f = d & 3;
        size_t p = vi ? (size_t)(n * 4 + f) : (size_t)(f * NQ + n);
        Ob[((size_t)(b * CC) + cch) * HW + p] = acc[d];
    }
}

// ---------- K8: product in sorted domain, scatter to original positions via idxv ----------
__global__ void k_prod_scatter(const float* __restrict__ O1, const float* __restrict__ O2,
                               const int* __restrict__ idxv, float* __restrict__ pu) {
    int j = blockIdx.x * 256 + threadIdx.x;
    int row = blockIdx.y;
    size_t o = (size_t)row * HW + j;
    int p = idxv[o];
    pu[(size_t)row * HW + p] = O1[o] * O2[o];
}

// ---------- K9: proj GEMM 64x64 ----------
__global__ __launch_bounds__(256) void k_gemm_proj(const float* __restrict__ wp, const float* __restrict__ pu,
                                                   float* __restrict__ op) {
    __shared__ float wt[4096];  // wt[c*64+m] = wp[m*64+c]
    int tid = threadIdx.x;
    for (int l = 0; l < 16; ++l) {
        int i = l * 256 + tid;
        int m = i >> 6, c = i & 63;
        wt[c * 64 + m] = wp[i];
    }
    __syncthreads();
    int b = blockIdx.y;
    int n = blockIdx.x * 256 + tid;
    float acc[64];
    #pragma unroll
    for (int m = 0; m < 64; ++m) acc[m] = 0.f;
    const float* src = pu + (size_t)(b * CC) * HW + n;
    for (int c = 0; c < 64; ++c) {
        float xv = src[(size_t)c * HW];
        const float* wr = &wt[c * 64];
        #pragma unroll
        for (int m4 = 0; m4 < 16; ++m4) {
            float4 w4 = *(const float4*)&wr[m4 * 4];
            acc[m4 * 4 + 0] = fmaf(w4.x, xv, acc[m4 * 4 + 0]);
            acc[m4 * 4 + 1] = fmaf(w4.y, xv, acc[m4 * 4 + 1]);
            acc[m4 * 4 + 2] = fmaf(w4.z, xv, acc[m4 * 4 + 2]);
            acc[m4 * 4 + 3] = fmaf(w4.w, xv, acc[m4 * 4 + 3]);
        }
    }
    float* dst = op + (size_t)(b * CC) * HW + n;
    for (int m = 0; m < 64; ++m) dst[(size_t)m * HW] = acc[m];
}

// ---------- K10: spatial unsort scatter for c<32, copy c>=32 ----------
__global__ void k_final(const float* __restrict__ op, const int* __restrict__ idx_h,
                        const int* __restrict__ idx_w, float* __restrict__ out) {
    int i = blockIdx.x * 256 + threadIdx.x;
    int p = i % HW;
    int c = (i / HW) % CC;
    int b = i / (HW * CC);
    float v = op[i];
    if (c < CHF) {
        int h = p / IMW, w = p % IMW;
        size_t ib = ((size_t)(b * CHF) + c) * HW;
        int W0 = idx_w[ib + h * IMW + w];
        int H0 = idx_h[ib + h * IMW + W0];
        out[((size_t)(b * CC) + c) * HW + H0 * IMW + W0] = v;
    } else {
        out[i] = v;
    }
}

extern "C" void kernel_launch(void* const* d_in, const int* in_sizes, int n_in,
                              void* d_out, int out_size, void* d_ws, size_t ws_size,
                              hipStream_t stream) {
    (void)in_sizes; (void)n_in; (void)out_size; (void)ws_size;
    const float* x    = (const float*)d_in[0];
    const float* temp = (const float*)d_in[1];
    const float* wq   = (const float*)d_in[2];
    const float* wd3  = (const float*)d_in[3];
    const float* wd5  = (const float*)d_in[4];
    const float* wd7  = (const float*)d_in[5];
    const float* wf   = (const float*)d_in[6];
    const float* bf   = (const float*)d_in[7];
    const float* wp   = (const float*)d_in[8];
    float* out = (float*)d_out;
    float* ws = (float*)d_ws;

    // ---- workspace arena: peak 59,768,832 floats = 239,075,328 B (~228 MiB) ----
    // R0: [0, 4718592)           idx_h (int, 2359296) + idx_w (int, 2359296)   [live to end]
    // R1: [4718592, 12582912)    A (4718592) then slice chunk (7864320)        [then idxv+partials]
    // R2: [12582912, 36175872)   q (23592960)                                  [then keyA|keyB|vs]
    // R3: [36175872, 59768832)   qkv (23592960)                                [then O1|O2|pu|op]
    int*      idx_h = (int*)(ws + 0);
    int*      idx_w = (int*)(ws + 2359296);
    float*    A     = ws + 4718592;
    float*    slice = ws + 4718592;                    // over dead A
    float*    q     = ws + 12582912;
    float*    qkv   = ws + 36175872;
    // sort-phase overlays (q dead):
    uint64_t* keyA  = (uint64_t*)(ws + 12582912);      // 4718592 u64
    uint64_t* keyB  = (uint64_t*)(ws + 22020096);      // 4718592 u64
    float*    vs    = ws + 31457280;                   // 4718592 (ends exactly at qkv)
    // attn-phase overlays (A/slice dead):
    int*      idxv  = (int*)(ws + 4718592);            // 4718592
    float*    partS = ws + 9437184;                    // 1048576
    float*    partN = ws + 10485760;                   // 32768
    float*    attnT = ws + 10518528;                   // 65536 (ends 10584064 < 12582912)
    // tail overlays (qkv dead after attn_qk):
    float*    O1    = ws + 36175872;
    float*    O2    = ws + 40894464;
    float*    pu    = ws + 45613056;
    float*    op    = ws + 50331648;                   // ends 55050240 < 59768832

    k_copy_back<<<9216, 256, 0, stream>>>(x, A);
    k_sort_h<<<12288, 128, 0, stream>>>(x, A, idx_h);
    k_sort_w<<<12288, 128, 0, stream>>>(A, idx_w);
    k_gemm_q<<<dim3(576, 5, 2), 256, 0, stream>>>(wq, A, q);

    for (int g = 0; g < 3; ++g) {
        for (int chunk = 0; chunk < 3; ++chunk) {
            int r0 = chunk * CROWS;
            if (g == 0)      k_dwconv<3><<<dim3(12, 320, 2), 256, 0, stream>>>(q, wd3, slice, r0);
            else if (g == 1) k_dwconv<5><<<dim3(12, 320, 2), 256, 0, stream>>>(q, wd5, slice, r0);
            else             k_dwconv<7><<<dim3(12, 320, 2), 256, 0, stream>>>(q, wd7, slice, r0);
            k_gemm_fuse<<<dim3(96, 5, 2), 256, 0, stream>>>(wf, slice, bf, qkv, g, r0);
        }
    }

    k_build_keys<<<dim3(144, 128), 256, 0, stream>>>(qkv, keyA);
    const int shifts[6] = {32, 38, 44, 50, 56, 62};
    for (int p = 0; p < 6; ++p) {
        if (p & 1) k_radix_pass<<<128, 256, 0, stream>>>(keyB, keyA, shifts[p]);
        else       k_radix_pass<<<128, 256, 0, stream>>>(keyA, keyB, shifts[p]);
    }
    k_unpack<<<dim3(144, 128), 256, 0, stream>>>(keyA, vs, idxv);

    k_attn_qk<<<dim3(16, 16), 256, 0, stream>>>(qkv, idxv, partS, partN);
    k_attn_softmax<<<16, 256, 0, stream>>>(partS, partN, temp, attnT);
    k_attn_av<<<dim3(36, 16), 256, 0, stream>>>(attnT, vs, O1, O2);

    k_prod_scatter<<<dim3(144, 128), 256, 0, stream>>>(O1, O2, idxv, pu);
    k_gemm_proj<<<dim3(144, 2), 256, 0, stream>>>(wp, pu, op);
    k_final<<<18432, 256, 0, stream>>>(op, idx_h, idx_w, out);
}

// Round 3
// 1950.660 us; speedup vs baseline: 1.0434x; 1.0434x over previous
//
#include <hip/hip_runtime.h>
#include <stdint.h>
#include <stddef.h>

constexpr int IMH = 192;
constexpr int IMW = 192;
constexpr int HW  = 36864;   // 192*192
constexpr int BB  = 2;
constexpr int CC  = 64;
constexpr int CHF = 32;      // half channels (sorted part)
constexpr int C5  = 320;     // 5*CC
constexpr int NQ  = 9216;    // HW/4
constexpr int CROWS = 64;    // fuse-pipeline chunk rows
constexpr int CHWN  = CROWS * IMW;  // 12288 cols per chunk
constexpr int NCHUNK = 32;   // attn_qk n-chunks per z
constexpr int CHN = HW / 4 / NCHUNK;  // 288 n per chunk

// ---------- float <-> monotone uint32 (order-preserving, invertible) ----------
static __device__ __forceinline__ uint32_t f2s(float f) {
    uint32_t u = __float_as_uint(f);
    return (u & 0x80000000u) ? ~u : (u | 0x80000000u);
}
static __device__ __forceinline__ float s2f(uint32_t s) {
    uint32_t u = (s & 0x80000000u) ? (s & 0x7FFFFFFFu) : ~s;
    return __uint_as_float(u);
}

// ---------- bitonic sort of 256 u64 keys in LDS (128 threads) ----------
static __device__ void bitonic256(uint64_t* keys, int tid) {
    for (unsigned k = 2; k <= 256; k <<= 1) {
        for (unsigned j = k >> 1; j; j >>= 1) {
            __syncthreads();
            unsigned i = ((tid & ~(j - 1)) << 1) | (tid & (j - 1));
            unsigned p = i | j;
            bool up = ((i & k) == 0);
            uint64_t a = keys[i], b = keys[p];
            if ((a > b) == up) { keys[i] = b; keys[p] = a; }
        }
    }
    __syncthreads();
}

// ---------- K0: copy unsorted half channels into A ----------
__global__ void k_copy_back(const float* __restrict__ x, float* __restrict__ A) {
    int i = blockIdx.x * 256 + threadIdx.x;        // over BB*CHF*HW
    int b = i / (CHF * HW);
    int r = i % (CHF * HW);
    size_t o = ((size_t)(b * CC) + CHF) * HW + r;
    A[o] = x[o];
}

// ---------- K1: stable sort along H (per b,c,w column), write A + idx_h ----------
__global__ __launch_bounds__(128) void k_sort_h(const float* __restrict__ x, float* __restrict__ A,
                                                int* __restrict__ idx_h) {
    __shared__ uint64_t keys[256];
    int tid = threadIdx.x;
    int blk = blockIdx.x;
    int w = blk % IMW;
    int c = (blk / IMW) % CHF;
    int b = blk / (IMW * CHF);
    const float* col = x + ((size_t)(b * CC) + c) * HW + w;
    for (int i = tid; i < 256; i += 128)
        keys[i] = (i < IMH) ? ((((uint64_t)f2s(col[(size_t)i * IMW])) << 32) | (uint32_t)i) : ~0ull;
    bitonic256(keys, tid);
    float* ocol = A + ((size_t)(b * CC) + c) * HW + w;
    int* icol = idx_h + ((size_t)(b * CHF) + c) * HW + w;
    for (int i = tid; i < IMH; i += 128) {
        uint64_t k = keys[i];
        ocol[(size_t)i * IMW] = s2f((uint32_t)(k >> 32));
        icol[(size_t)i * IMW] = (int)(k & 0xFFFFFFFFull);
    }
}

// ---------- K2: stable sort along W (per b,c,h row), in-place on A, write idx_w ----------
__global__ __launch_bounds__(128) void k_sort_w(float* __restrict__ A, int* __restrict__ idx_w) {
    __shared__ uint64_t keys[256];
    int tid = threadIdx.x;
    int blk = blockIdx.x;
    int h = blk % IMH;
    int c = (blk / IMH) % CHF;
    int b = blk / (IMH * CHF);
    float* row = A + ((size_t)(b * CC) + c) * HW + (size_t)h * IMW;
    for (int i = tid; i < 256; i += 128)
        keys[i] = (i < IMW) ? ((((uint64_t)f2s(row[i])) << 32) | (uint32_t)i) : ~0ull;
    bitonic256(keys, tid);
    int* irow = idx_w + ((size_t)(b * CHF) + c) * HW + (size_t)h * IMW;
    for (int i = tid; i < IMW; i += 128) {
        uint64_t k = keys[i];
        row[i] = s2f((uint32_t)(k >> 32));
        irow[i] = (int)(k & 0xFFFFFFFFull);
    }
}

// ---------- K3: q = W_qkv(320x64) * A(64xHW) per batch ----------
__global__ __launch_bounds__(256) void k_gemm_q(const float* __restrict__ wq, const float* __restrict__ A,
                                                float* __restrict__ q) {
    __shared__ float Wt[64][68];
    __shared__ float Xt[64][68];
    int tid = threadIdx.x;
    int n0 = blockIdx.x * 64, m0 = blockIdx.y * 64, b = blockIdx.z;
    for (int l = 0; l < 16; ++l) {
        int idx = l * 256 + tid;
        int cc = idx & 63, m = idx >> 6;
        Wt[cc][m] = wq[(size_t)(m0 + m) * 64 + cc];
    }
    for (int l = 0; l < 16; ++l) {
        int idx = l * 256 + tid;
        int n = idx & 63, cc = idx >> 6;
        Xt[cc][n] = A[((size_t)(b * CC) + cc) * HW + n0 + n];
    }
    __syncthreads();
    int ty = tid >> 4, tx = tid & 15;
    float acc[4][4] = {};
    for (int cc = 0; cc < 64; ++cc) {
        float4 av = *(const float4*)&Wt[cc][ty * 4];
        float4 bv = *(const float4*)&Xt[cc][tx * 4];
        float aa[4] = {av.x, av.y, av.z, av.w};
        float bb[4] = {bv.x, bv.y, bv.z, bv.w};
        #pragma unroll
        for (int i = 0; i < 4; ++i)
            #pragma unroll
            for (int j = 0; j < 4; ++j)
                acc[i][j] = fmaf(aa[i], bb[j], acc[i][j]);
    }
    for (int i = 0; i < 4; ++i) {
        float4 o;
        o.x = acc[i][0]; o.y = acc[i][1]; o.z = acc[i][2]; o.w = acc[i][3];
        *(float4*)&q[((size_t)(b * C5) + m0 + ty * 4 + i) * HW + n0 + tx * 4] = o;
    }
}

// ---------- K4: depthwise conv KSxKS (zero pad) for a 64-row chunk starting at r0 ----------
template <int KS>
__global__ __launch_bounds__(256) void k_dwconv(const float* __restrict__ q, const float* __restrict__ wd,
                                                float* __restrict__ slice, int r0) {
    constexpr int PAD = KS / 2;
    constexpr int EXT = 32 + 2 * PAD;
    __shared__ float tile[EXT][EXT];
    int tid = threadIdx.x;
    int b = blockIdx.z, c = blockIdx.y;
    int t = blockIdx.x;                  // 12 tiles: 2 tile-rows x 6 tile-cols
    int ty0 = r0 + (t / 6) * 32, tx0 = (t % 6) * 32;
    const float* src = q + ((size_t)(b * C5) + c) * HW;
    for (int i = tid; i < EXT * EXT; i += 256) {
        int iy = i / EXT, ix = i % EXT;
        int gy = ty0 + iy - PAD, gx = tx0 + ix - PAD;
        float v = 0.f;
        if (gy >= 0 && gy < IMH && gx >= 0 && gx < IMW) v = src[gy * IMW + gx];
        tile[iy][ix] = v;
    }
    __syncthreads();
    float wreg[KS * KS];
    #pragma unroll
    for (int i = 0; i < KS * KS; ++i) wreg[i] = wd[(size_t)c * KS * KS + i];
    float* dst = slice + ((size_t)(b * C5) + c) * CHWN;
    #pragma unroll
    for (int k = 0; k < 4; ++k) {
        int pix = k * 256 + tid;
        int py = pix >> 5, px = pix & 31;
        float acc = 0.f;
        #pragma unroll
        for (int ky = 0; ky < KS; ++ky)
            #pragma unroll
            for (int kx = 0; kx < KS; ++kx)
                acc = fmaf(tile[py + ky][px + kx], wreg[ky * KS + kx], acc);
        dst[(ty0 - r0 + py) * IMW + tx0 + px] = acc;
    }
}

// ---------- K5: qkv(chunk) (+)= W_fuse[:, g*320:(g+1)*320] * slice(chunk) ----------
// 64x256 tile, 8x8 acc per thread, BK=8, split-half n fragments (tx*4 and 128+tx*4).
__global__ __launch_bounds__(256) void k_gemm_fuse(const float* __restrict__ wf, const float* __restrict__ slice,
                                                   const float* __restrict__ bias, float* __restrict__ qkv,
                                                   int g, int r0) {
    __shared__ float Wt[8][72];
    __shared__ float Xt[8][260];
    int tid = threadIdx.x;
    int n0 = blockIdx.x * 256, m0 = blockIdx.y * 64, b = blockIdx.z;
    int gk = g * 320;
    int ty = tid >> 5, tx = tid & 31;    // 8 x 32
    float acc[8][8] = {};
    // staging index precompute
    int wm = tid >> 2, wkk = (tid & 3) << 1;             // Wt: 64 m x (2 kk) per thread
    int xkk = tid >> 5, xn = (tid & 31) * 8;             // Xt: 8 kk x 8 n per thread
    for (int k0 = 0; k0 < 320; k0 += 8) {
        __syncthreads();
        {
            const float* wsrc = &wf[(size_t)(m0 + wm) * 960 + gk + k0 + wkk];
            float2 w2 = *(const float2*)wsrc;
            Wt[wkk][wm] = w2.x;
            Wt[wkk + 1][wm] = w2.y;
            const float* xsrc = &slice[((size_t)(b * C5) + k0 + xkk) * CHWN + n0 + xn];
            float4 x0 = *(const float4*)xsrc;
            float4 x1 = *(const float4*)(xsrc + 4);
            *(float4*)&Xt[xkk][xn] = x0;
            *(float4*)&Xt[xkk][xn + 4] = x1;
        }
        __syncthreads();
        #pragma unroll
        for (int kk = 0; kk < 8; ++kk) {
            float4 a0 = *(const float4*)&Wt[kk][ty * 8];
            float4 a1 = *(const float4*)&Wt[kk][ty * 8 + 4];
            float4 b0 = *(const float4*)&Xt[kk][tx * 4];
            float4 b1 = *(const float4*)&Xt[kk][128 + tx * 4];
            float aa[8] = {a0.x, a0.y, a0.z, a0.w, a1.x, a1.y, a1.z, a1.w};
            float bb[8] = {b0.x, b0.y, b0.z, b0.w, b1.x, b1.y, b1.z, b1.w};
            #pragma unroll
            for (int i = 0; i < 8; ++i)
                #pragma unroll
                for (int j = 0; j < 8; ++j)
                    acc[i][j] = fmaf(aa[i], bb[j], acc[i][j]);
        }
    }
    #pragma unroll
    for (int i = 0; i < 8; ++i) {
        int m = m0 + ty * 8 + i;
        size_t base = ((size_t)(b * C5) + m) * HW + (size_t)r0 * IMW + n0;
        float* p0 = &qkv[base + tx * 4];
        float* p1 = &qkv[base + 128 + tx * 4];
        if (g == 0) {
            float bv = bias[m];
            float4 o0, o1;
            o0.x = acc[i][0] + bv; o0.y = acc[i][1] + bv; o0.z = acc[i][2] + bv; o0.w = acc[i][3] + bv;
            o1.x = acc[i][4] + bv; o1.y = acc[i][5] + bv; o1.z = acc[i][6] + bv; o1.w = acc[i][7] + bv;
            *(float4*)p0 = o0;
            *(float4*)p1 = o1;
        } else {
            float4 c0 = *(const float4*)p0;
            float4 c1 = *(const float4*)p1;
            c0.x += acc[i][0]; c0.y += acc[i][1]; c0.z += acc[i][2]; c0.w += acc[i][3];
            c1.x += acc[i][4]; c1.y += acc[i][5]; c1.z += acc[i][6]; c1.w += acc[i][7];
            *(float4*)p0 = c0;
            *(float4*)p1 = c1;
        }
    }
}

// ---------- K6a: build (value || index) u64 keys for v rows ----------
__global__ void k_build_keys(const float* __restrict__ qkv, uint64_t* __restrict__ keyA) {
    int j = blockIdx.x * 256 + threadIdx.x;
    int row = blockIdx.y;               // b*64+c
    int b = row >> 6, c = row & 63;
    float v = qkv[((size_t)(b * C5) + 256 + c) * HW + j];
    keyA[(size_t)row * HW + j] = (((uint64_t)f2s(v)) << 32) | (uint32_t)j;
}

// ---------- K6b: one stable LSD radix pass (6-bit digit), one block per row ----------
__global__ __launch_bounds__(256) void k_radix_pass(const uint64_t* __restrict__ in, uint64_t* __restrict__ out,
                                                    int shift) {
    __shared__ uint16_t cnt[256][66];
    __shared__ uint32_t base[64];
    int t = threadIdx.x;
    int row = blockIdx.x;
    const uint64_t* src = in + (size_t)row * HW;
    uint64_t* dst = out + (size_t)row * HW;
    for (int d = 0; d < 66; ++d) cnt[t][d] = 0;
    __syncthreads();
    const int CHUNK = HW / 256;  // 144
    int s0 = t * CHUNK;
    for (int i = 0; i < CHUNK; ++i) {
        unsigned d = (unsigned)(src[s0 + i] >> shift) & 63u;
        cnt[t][d] = (uint16_t)(cnt[t][d] + 1);
    }
    __syncthreads();
    if (t < 64) {
        uint32_t s = 0;
        for (int tt = 0; tt < 256; ++tt) {
            uint32_t cv = cnt[tt][t];
            cnt[tt][t] = (uint16_t)s;
            s += cv;
        }
        base[t] = s;
    }
    __syncthreads();
    if (t == 0) {
        uint32_t s = 0;
        for (int d = 0; d < 64; ++d) { uint32_t cv = base[d]; base[d] = s; s += cv; }
    }
    __syncthreads();
    for (int i = 0; i < CHUNK; ++i) {
        uint64_t k = src[s0 + i];
        unsigned d = (unsigned)(k >> shift) & 63u;
        uint32_t pos = base[d] + cnt[t][d];
        cnt[t][d] = (uint16_t)(cnt[t][d] + 1);
        dst[pos] = k;
    }
}

// ---------- K6c: unpack sorted keys -> vs, idxv ----------
__global__ void k_unpack(const uint64_t* __restrict__ keys, float* __restrict__ vs, int* __restrict__ idxv) {
    int j = blockIdx.x * 256 + threadIdx.x;
    int row = blockIdx.y;
    size_t o = (size_t)row * HW + j;
    uint64_t k = keys[o];
    vs[o] = s2f((uint32_t)(k >> 32));
    idxv[o] = (int)(k & 0xFFFFFFFFull);
}

// ---------- K6d: gather q1,k1,q2,k2 into sorted order, contiguous g4 ----------
// one block per (b,c) row: working set = idxv row (144KB) + 4 qkv rows -> L2-local
__global__ __launch_bounds__(1024) void k_gather4(const int* __restrict__ idxv, const float* __restrict__ qkv,
                                                  float* __restrict__ g4) {
    int row = blockIdx.x;                 // b*64 + cg
    int b = row >> 6, cg = row & 63;
    const int* irow = idxv + (size_t)row * HW;
    const float* qb = qkv + (size_t)(b * C5) * HW + (size_t)cg * HW;
    size_t S4 = (size_t)BB * CC * HW;     // 4718592
    float* d0 = g4 + (size_t)row * HW;
    for (int j = threadIdx.x; j < HW; j += 1024) {
        int p = irow[j];
        d0[j]           = qb[p];                       // q1
        d0[S4 + j]      = qb[(size_t)64 * HW + p];     // k1
        d0[2 * S4 + j]  = qb[(size_t)128 * HW + p];    // q2
        d0[3 * S4 + j]  = qb[(size_t)192 * HW + p];    // k2
    }
}

// ---------- K7a: S partials + norm^2 partials, streaming from g4 ----------
__global__ __launch_bounds__(256) void k_attn_qk(const float* __restrict__ g4,
                                                 float* __restrict__ partS, float* __restrict__ partN) {
    __shared__ float Qs[16][68];
    __shared__ float Ks[16][68];
    __shared__ float nqs[4][64];
    __shared__ float nks[4][64];
    int tid = threadIdx.x;
    int ychunk = blockIdx.x;   // NCHUNK chunks of CHN
    int z = blockIdx.y;        // 16 = b(2) x h(4) x variant(2)
    int vi = z & 1, hh = (z >> 1) & 3, b = z >> 3;
    size_t S4 = (size_t)BB * CC * HW;
    const float* Q = g4 + (vi ? 2 * S4 : (size_t)0);
    const float* Kp = g4 + (vi ? 3 * S4 : S4);
    int ty = tid >> 4, tx = tid & 15;
    float acc[4][4] = {};
    float nq = 0.f, nk = 0.f;
    int d0 = tid & 63, kset = tid >> 6;
    int nbase0 = ychunk * CHN;
    for (int it = 0; it < CHN / 16; ++it) {
        int nb0 = nbase0 + it * 16;
        __syncthreads();
        #pragma unroll
        for (int l = 0; l < 4; ++l) {
            int idx = l * 256 + tid;
            int d = idx >> 4, kk = idx & 15;
            int n = nb0 + kk;
            int cch = hh * 16 + (d >> 2), f = d & 3;
            size_t off = ((size_t)(b * CC) + cch) * HW + (vi ? (size_t)(n * 4 + f) : (size_t)(f * NQ + n));
            Qs[kk][d] = Q[off];
            Ks[kk][d] = Kp[off];
        }
        __syncthreads();
        #pragma unroll
        for (int kk = 0; kk < 16; ++kk) {
            float4 av = *(const float4*)&Qs[kk][ty * 4];
            float4 bv = *(const float4*)&Ks[kk][tx * 4];
            float aa[4] = {av.x, av.y, av.z, av.w};
            float bb[4] = {bv.x, bv.y, bv.z, bv.w};
            #pragma unroll
            for (int i = 0; i < 4; ++i)
                #pragma unroll
                for (int j = 0; j < 4; ++j)
                    acc[i][j] = fmaf(aa[i], bb[j], acc[i][j]);
        }
        #pragma unroll
        for (int kk2 = 0; kk2 < 4; ++kk2) {
            float qv = Qs[kset * 4 + kk2][d0];
            float kv = Ks[kset * 4 + kk2][d0];
            nq = fmaf(qv, qv, nq);
            nk = fmaf(kv, kv, nk);
        }
    }
    size_t sb = ((size_t)z * NCHUNK + ychunk) * 4096;
    #pragma unroll
    for (int i = 0; i < 4; ++i)
        #pragma unroll
        for (int j = 0; j < 4; ++j)
            partS[sb + (size_t)(ty * 4 + i) * 64 + tx * 4 + j] = acc[i][j];
    nqs[kset][d0] = nq;
    nks[kset][d0] = nk;
    __syncthreads();
    if (tid < 64) {
        float sq = nqs[0][tid] + nqs[1][tid] + nqs[2][tid] + nqs[3][tid];
        float sk = nks[0][tid] + nks[1][tid] + nks[2][tid] + nks[3][tid];
        size_t nb2 = ((size_t)z * NCHUNK + ychunk) * 128;
        partN[nb2 + tid] = sq;
        partN[nb2 + 64 + tid] = sk;
    }
}

// ---------- K7b: reduce partials, normalize, exp, denom = rowsum+1 ; write attn^T ----------
__global__ __launch_bounds__(256) void k_attn_softmax(const float* __restrict__ partS,
                                                      const float* __restrict__ partN,
                                                      const float* __restrict__ temp, float* __restrict__ attnT) {
    __shared__ float nqv[64], nkv[64];
    __shared__ float pbuf[64][65];
    __shared__ float rred[64][4];
    __shared__ float rsum[64];
    int tid = threadIdx.x;
    int z = blockIdx.x;
    int hh = (z >> 1) & 3;
    if (tid < 128) {
        float s = 0.f;
        for (int ch = 0; ch < NCHUNK; ++ch) s += partN[((size_t)z * NCHUNK + ch) * 128 + tid];
        float nv = fmaxf(sqrtf(s), 1e-12f);
        if (tid < 64) nqv[tid] = nv; else nkv[tid - 64] = nv;
    }
    __syncthreads();
    float tf = temp[hh];
    int d = tid >> 2, qq = tid & 3;
    float psum = 0.f;
    for (int e = qq * 16; e < qq * 16 + 16; ++e) {
        float s = 0.f;
        for (int ch = 0; ch < NCHUNK; ++ch) s += partS[((size_t)z * NCHUNK + ch) * 4096 + (size_t)d * 64 + e];
        float p = expf(tf * s / (nqv[d] * nkv[e]));
        pbuf[d][e] = p;
        psum += p;
    }
    rred[d][qq] = psum;
    __syncthreads();
    if (tid < 64) rsum[tid] = rred[tid][0] + rred[tid][1] + rred[tid][2] + rred[tid][3] + 1.0f;
    __syncthreads();
    for (int e = qq * 16; e < qq * 16 + 16; ++e)
        attnT[(size_t)z * 4096 + (size_t)e * 64 + d] = pbuf[d][e] / rsum[d];
}

// ---------- K7c: O = attn * V, written back to (c, sorted-position) layout ----------
__global__ __launch_bounds__(256) void k_attn_av(const float* __restrict__ attnT, const float* __restrict__ vs,
                                                 float* __restrict__ O1, float* __restrict__ O2) {
    __shared__ float at_s[4096];
    int tid = threadIdx.x;
    int z = blockIdx.y;
    int vi = z & 1, hh = (z >> 1) & 3, b = z >> 3;
    for (int l = 0; l < 16; ++l) at_s[l * 256 + tid] = attnT[(size_t)z * 4096 + l * 256 + tid];
    __syncthreads();
    int n = blockIdx.x * 256 + tid;
    float acc[64];
    #pragma unroll
    for (int d = 0; d < 64; ++d) acc[d] = 0.f;
    for (int e = 0; e < 64; ++e) {
        int cch = hh * 16 + (e >> 2), f = e & 3;
        size_t p = vi ? (size_t)(n * 4 + f) : (size_t)(f * NQ + n);
        float vv = vs[((size_t)(b * CC) + cch) * HW + p];
        const float* ar = &at_s[e * 64];
        #pragma unroll
        for (int d4 = 0; d4 < 16; ++d4) {
            float4 a4 = *(const float4*)&ar[d4 * 4];
            acc[d4 * 4 + 0] = fmaf(a4.x, vv, acc[d4 * 4 + 0]);
            acc[d4 * 4 + 1] = fmaf(a4.y, vv, acc[d4 * 4 + 1]);
            acc[d4 * 4 + 2] = fmaf(a4.z, vv, acc[d4 * 4 + 2]);
            acc[d4 * 4 + 3] = fmaf(a4.w, vv, acc[d4 * 4 + 3]);
        }
    }
    float* Ob = vi ? O2 : O1;
    #pragma unroll
    for (int d = 0; d < 64; ++d) {
        int cch = hh * 16 + (d >> 2), f = d & 3;
        size_t p = vi ? (size_t)(n * 4 + f) : (size_t)(f * NQ + n);
        Ob[((size_t)(b * CC) + cch) * HW + p] = acc[d];
    }
}

// ---------- K8: product in sorted domain, scatter to original positions via idxv ----------
__global__ void k_prod_scatter(const float* __restrict__ O1, const float* __restrict__ O2,
                               const int* __restrict__ idxv, float* __restrict__ pu) {
    int j = blockIdx.x * 256 + threadIdx.x;
    int row = blockIdx.y;
    size_t o = (size_t)row * HW + j;
    int p = idxv[o];
    pu[(size_t)row * HW + p] = O1[o] * O2[o];
}

// ---------- K9: proj GEMM 64x64 ----------
__global__ __launch_bounds__(256) void k_gemm_proj(const float* __restrict__ wp, const float* __restrict__ pu,
                                                   float* __restrict__ op) {
    __shared__ float wt[4096];  // wt[c*64+m] = wp[m*64+c]
    int tid = threadIdx.x;
    for (int l = 0; l < 16; ++l) {
        int i = l * 256 + tid;
        int m = i >> 6, c = i & 63;
        wt[c * 64 + m] = wp[i];
    }
    __syncthreads();
    int b = blockIdx.y;
    int n = blockIdx.x * 256 + tid;
    float acc[64];
    #pragma unroll
    for (int m = 0; m < 64; ++m) acc[m] = 0.f;
    const float* src = pu + (size_t)(b * CC) * HW + n;
    for (int c = 0; c < 64; ++c) {
        float xv = src[(size_t)c * HW];
        const float* wr = &wt[c * 64];
        #pragma unroll
        for (int m4 = 0; m4 < 16; ++m4) {
            float4 w4 = *(const float4*)&wr[m4 * 4];
            acc[m4 * 4 + 0] = fmaf(w4.x, xv, acc[m4 * 4 + 0]);
            acc[m4 * 4 + 1] = fmaf(w4.y, xv, acc[m4 * 4 + 1]);
            acc[m4 * 4 + 2] = fmaf(w4.z, xv, acc[m4 * 4 + 2]);
            acc[m4 * 4 + 3] = fmaf(w4.w, xv, acc[m4 * 4 + 3]);
        }
    }
    float* dst = op + (size_t)(b * CC) * HW + n;
    for (int m = 0; m < 64; ++m) dst[(size_t)m * HW] = acc[m];
}

// ---------- K10: spatial unsort scatter for c<32, copy c>=32 ----------
__global__ void k_final(const float* __restrict__ op, const int* __restrict__ idx_h,
                        const int* __restrict__ idx_w, float* __restrict__ out) {
    int i = blockIdx.x * 256 + threadIdx.x;
    int p = i % HW;
    int c = (i / HW) % CC;
    int b = i / (HW * CC);
    float v = op[i];
    if (c < CHF) {
        int h = p / IMW, w = p % IMW;
        size_t ib = ((size_t)(b * CHF) + c) * HW;
        int W0 = idx_w[ib + h * IMW + w];
        int H0 = idx_h[ib + h * IMW + W0];
        out[((size_t)(b * CC) + c) * HW + H0 * IMW + W0] = v;
    } else {
        out[i] = v;
    }
}

extern "C" void kernel_launch(void* const* d_in, const int* in_sizes, int n_in,
                              void* d_out, int out_size, void* d_ws, size_t ws_size,
                              hipStream_t stream) {
    (void)in_sizes; (void)n_in; (void)out_size; (void)ws_size;
    const float* x    = (const float*)d_in[0];
    const float* temp = (const float*)d_in[1];
    const float* wq   = (const float*)d_in[2];
    const float* wd3  = (const float*)d_in[3];
    const float* wd5  = (const float*)d_in[4];
    const float* wd7  = (const float*)d_in[5];
    const float* wf   = (const float*)d_in[6];
    const float* bf   = (const float*)d_in[7];
    const float* wp   = (const float*)d_in[8];
    float* out = (float*)d_out;
    float* ws = (float*)d_ws;

    // ---- workspace arena: peak 59,768,832 floats (~228 MiB), same as round-2 ----
    // R0: [0, 4718592)            idx_h + idx_w (int)                [live to end]
    // R1: [4718592, 12582912)     A / slice, then idxv               
    // R2: [12582912, 36175872)    q, then keyA|keyB, then g4 (18874368) ending at vs
    //     vs @ [31457280, 36175872)
    // R3: [36175872, 59768832)    qkv, then O1|O2|pu|op|partS|partN|attnT
    int*      idx_h = (int*)(ws + 0);
    int*      idx_w = (int*)(ws + 2359296);
    float*    A     = ws + 4718592;
    float*    slice = ws + 4718592;                    // over dead A
    float*    q     = ws + 12582912;
    float*    qkv   = ws + 36175872;
    uint64_t* keyA  = (uint64_t*)(ws + 12582912);      // over dead q
    uint64_t* keyB  = (uint64_t*)(ws + 22020096);
    float*    vs    = ws + 31457280;
    int*      idxv  = (int*)(ws + 4718592);            // over dead slice
    float*    g4    = ws + 12582912;                   // over dead keyA+keyB (exactly 18874368)
    // after k_gather4, qkv is dead:
    float*    O1    = ws + 36175872;
    float*    O2    = ws + 40894464;
    float*    pu    = ws + 45613056;
    float*    op    = ws + 50331648;                   // ends 55050240
    float*    partS = ws + 55050240;                   // 16*32*4096 = 2097152
    float*    partN = ws + 57147392;                   // 16*32*128 = 65536
    float*    attnT = ws + 57212928;                   // 65536 -> ends 57278464 < 59768832

    k_copy_back<<<9216, 256, 0, stream>>>(x, A);
    k_sort_h<<<12288, 128, 0, stream>>>(x, A, idx_h);
    k_sort_w<<<12288, 128, 0, stream>>>(A, idx_w);
    k_gemm_q<<<dim3(576, 5, 2), 256, 0, stream>>>(wq, A, q);

    for (int g = 0; g < 3; ++g) {
        for (int chunk = 0; chunk < 3; ++chunk) {
            int r0 = chunk * CROWS;
            if (g == 0)      k_dwconv<3><<<dim3(12, 320, 2), 256, 0, stream>>>(q, wd3, slice, r0);
            else if (g == 1) k_dwconv<5><<<dim3(12, 320, 2), 256, 0, stream>>>(q, wd5, slice, r0);
            else             k_dwconv<7><<<dim3(12, 320, 2), 256, 0, stream>>>(q, wd7, slice, r0);
            k_gemm_fuse<<<dim3(48, 5, 2), 256, 0, stream>>>(wf, slice, bf, qkv, g, r0);
        }
    }

    k_build_keys<<<dim3(144, 128), 256, 0, stream>>>(qkv, keyA);
    const int shifts[6] = {32, 38, 44, 50, 56, 62};
    for (int p = 0; p < 6; ++p) {
        if (p & 1) k_radix_pass<<<128, 256, 0, stream>>>(keyB, keyA, shifts[p]);
        else       k_radix_pass<<<128, 256, 0, stream>>>(keyA, keyB, shifts[p]);
    }
    k_unpack<<<dim3(144, 128), 256, 0, stream>>>(keyA, vs, idxv);
    k_gather4<<<128, 1024, 0, stream>>>(idxv, qkv, g4);

    k_attn_qk<<<dim3(NCHUNK, 16), 256, 0, stream>>>(g4, partS, partN);
    k_attn_softmax<<<16, 256, 0, stream>>>(partS, partN, temp, attnT);
    k_attn_av<<<dim3(36, 16), 256, 0, stream>>>(attnT, vs, O1, O2);

    k_prod_scatter<<<dim3(144, 128), 256, 0, stream>>>(O1, O2, idxv, pu);
    k_gemm_proj<<<dim3(144, 2), 256, 0, stream>>>(wp, pu, op);
    k_final<<<18432, 256, 0, stream>>>(op, idx_h, idx_w, out);
}

// Round 4
// 1654.272 us; speedup vs baseline: 1.2303x; 1.1792x over previous
//
#include <hip/hip_runtime.h>
#include <stdint.h>
#include <stddef.h>

constexpr int IMH = 192;
constexpr int IMW = 192;
constexpr int HW  = 36864;   // 192*192
constexpr int BB  = 2;
constexpr int CC  = 64;
constexpr int CHF = 32;      // half channels (sorted part)
constexpr int C5  = 320;     // 5*CC
constexpr int NQ  = 9216;    // HW/4
constexpr int CROWS = 64;    // fuse-pipeline chunk rows
constexpr int CHWN  = CROWS * IMW;  // 12288 cols per chunk
constexpr int NCHUNK = 32;   // attn_qk n-chunks per z
constexpr int CHN = HW / 4 / NCHUNK;  // 288 n per chunk
constexpr int NSEG = 16;     // radix segments per row
constexpr int SEGN = HW / NSEG;      // 2304 elements per segment (= 9 * 256)

// ---------- float <-> monotone uint32 (order-preserving, invertible) ----------
static __device__ __forceinline__ uint32_t f2s(float f) {
    uint32_t u = __float_as_uint(f);
    return (u & 0x80000000u) ? ~u : (u | 0x80000000u);
}
static __device__ __forceinline__ float s2f(uint32_t s) {
    uint32_t u = (s & 0x80000000u) ? (s & 0x7FFFFFFFu) : ~s;
    return __uint_as_float(u);
}

// ---------- bitonic sort of 256 u64 keys in LDS (128 threads) ----------
static __device__ void bitonic256(uint64_t* keys, int tid) {
    for (unsigned k = 2; k <= 256; k <<= 1) {
        for (unsigned j = k >> 1; j; j >>= 1) {
            __syncthreads();
            unsigned i = ((tid & ~(j - 1)) << 1) | (tid & (j - 1));
            unsigned p = i | j;
            bool up = ((i & k) == 0);
            uint64_t a = keys[i], b = keys[p];
            if ((a > b) == up) { keys[i] = b; keys[p] = a; }
        }
    }
    __syncthreads();
}

// ---------- K0: copy unsorted half channels into A ----------
__global__ void k_copy_back(const float* __restrict__ x, float* __restrict__ A) {
    int i = blockIdx.x * 256 + threadIdx.x;        // over BB*CHF*HW
    int b = i / (CHF * HW);
    int r = i % (CHF * HW);
    size_t o = ((size_t)(b * CC) + CHF) * HW + r;
    A[o] = x[o];
}

// ---------- K1: stable sort along H (per b,c,w column), write A + idx_h ----------
__global__ __launch_bounds__(128) void k_sort_h(const float* __restrict__ x, float* __restrict__ A,
                                                int* __restrict__ idx_h) {
    __shared__ uint64_t keys[256];
    int tid = threadIdx.x;
    int blk = blockIdx.x;
    int w = blk % IMW;
    int c = (blk / IMW) % CHF;
    int b = blk / (IMW * CHF);
    const float* col = x + ((size_t)(b * CC) + c) * HW + w;
    for (int i = tid; i < 256; i += 128)
        keys[i] = (i < IMH) ? ((((uint64_t)f2s(col[(size_t)i * IMW])) << 32) | (uint32_t)i) : ~0ull;
    bitonic256(keys, tid);
    float* ocol = A + ((size_t)(b * CC) + c) * HW + w;
    int* icol = idx_h + ((size_t)(b * CHF) + c) * HW + w;
    for (int i = tid; i < IMH; i += 128) {
        uint64_t k = keys[i];
        ocol[(size_t)i * IMW] = s2f((uint32_t)(k >> 32));
        icol[(size_t)i * IMW] = (int)(k & 0xFFFFFFFFull);
    }
}

// ---------- K2: stable sort along W (per b,c,h row), in-place on A, write idx_w ----------
__global__ __launch_bounds__(128) void k_sort_w(float* __restrict__ A, int* __restrict__ idx_w) {
    __shared__ uint64_t keys[256];
    int tid = threadIdx.x;
    int blk = blockIdx.x;
    int h = blk % IMH;
    int c = (blk / IMH) % CHF;
    int b = blk / (IMH * CHF);
    float* row = A + ((size_t)(b * CC) + c) * HW + (size_t)h * IMW;
    for (int i = tid; i < 256; i += 128)
        keys[i] = (i < IMW) ? ((((uint64_t)f2s(row[i])) << 32) | (uint32_t)i) : ~0ull;
    bitonic256(keys, tid);
    int* irow = idx_w + ((size_t)(b * CHF) + c) * HW + (size_t)h * IMW;
    for (int i = tid; i < IMW; i += 128) {
        uint64_t k = keys[i];
        row[i] = s2f((uint32_t)(k >> 32));
        irow[i] = (int)(k & 0xFFFFFFFFull);
    }
}

// ---------- K3: q = W_qkv(320x64) * A(64xHW) per batch ----------
__global__ __launch_bounds__(256) void k_gemm_q(const float* __restrict__ wq, const float* __restrict__ A,
                                                float* __restrict__ q) {
    __shared__ float Wt[64][68];
    __shared__ float Xt[64][68];
    int tid = threadIdx.x;
    int n0 = blockIdx.x * 64, m0 = blockIdx.y * 64, b = blockIdx.z;
    for (int l = 0; l < 16; ++l) {
        int idx = l * 256 + tid;
        int cc = idx & 63, m = idx >> 6;
        Wt[cc][m] = wq[(size_t)(m0 + m) * 64 + cc];
    }
    for (int l = 0; l < 16; ++l) {
        int idx = l * 256 + tid;
        int n = idx & 63, cc = idx >> 6;
        Xt[cc][n] = A[((size_t)(b * CC) + cc) * HW + n0 + n];
    }
    __syncthreads();
    int ty = tid >> 4, tx = tid & 15;
    float acc[4][4] = {};
    for (int cc = 0; cc < 64; ++cc) {
        float4 av = *(const float4*)&Wt[cc][ty * 4];
        float4 bv = *(const float4*)&Xt[cc][tx * 4];
        float aa[4] = {av.x, av.y, av.z, av.w};
        float bb[4] = {bv.x, bv.y, bv.z, bv.w};
        #pragma unroll
        for (int i = 0; i < 4; ++i)
            #pragma unroll
            for (int j = 0; j < 4; ++j)
                acc[i][j] = fmaf(aa[i], bb[j], acc[i][j]);
    }
    for (int i = 0; i < 4; ++i) {
        float4 o;
        o.x = acc[i][0]; o.y = acc[i][1]; o.z = acc[i][2]; o.w = acc[i][3];
        *(float4*)&q[((size_t)(b * C5) + m0 + ty * 4 + i) * HW + n0 + tx * 4] = o;
    }
}

// ---------- K4: depthwise conv KSxKS (zero pad) for a 64-row chunk starting at r0 ----------
template <int KS>
__global__ __launch_bounds__(256) void k_dwconv(const float* __restrict__ q, const float* __restrict__ wd,
                                                float* __restrict__ slice, int r0) {
    constexpr int PAD = KS / 2;
    constexpr int EXT = 32 + 2 * PAD;
    __shared__ float tile[EXT][EXT];
    int tid = threadIdx.x;
    int b = blockIdx.z, c = blockIdx.y;
    int t = blockIdx.x;                  // 12 tiles: 2 tile-rows x 6 tile-cols
    int ty0 = r0 + (t / 6) * 32, tx0 = (t % 6) * 32;
    const float* src = q + ((size_t)(b * C5) + c) * HW;
    for (int i = tid; i < EXT * EXT; i += 256) {
        int iy = i / EXT, ix = i % EXT;
        int gy = ty0 + iy - PAD, gx = tx0 + ix - PAD;
        float v = 0.f;
        if (gy >= 0 && gy < IMH && gx >= 0 && gx < IMW) v = src[gy * IMW + gx];
        tile[iy][ix] = v;
    }
    __syncthreads();
    float wreg[KS * KS];
    #pragma unroll
    for (int i = 0; i < KS * KS; ++i) wreg[i] = wd[(size_t)c * KS * KS + i];
    float* dst = slice + ((size_t)(b * C5) + c) * CHWN;
    #pragma unroll
    for (int k = 0; k < 4; ++k) {
        int pix = k * 256 + tid;
        int py = pix >> 5, px = pix & 31;
        float acc = 0.f;
        #pragma unroll
        for (int ky = 0; ky < KS; ++ky)
            #pragma unroll
            for (int kx = 0; kx < KS; ++kx)
                acc = fmaf(tile[py + ky][px + kx], wreg[ky * KS + kx], acc);
        dst[(ty0 - r0 + py) * IMW + tx0 + px] = acc;
    }
}

// ---------- K5: qkv(chunk) (+)= W_fuse[:, g*320:(g+1)*320] * slice(chunk) ----------
__global__ __launch_bounds__(256) void k_gemm_fuse(const float* __restrict__ wf, const float* __restrict__ slice,
                                                   const float* __restrict__ bias, float* __restrict__ qkv,
                                                   int g, int r0) {
    __shared__ float Wt[8][72];
    __shared__ float Xt[8][260];
    int tid = threadIdx.x;
    int n0 = blockIdx.x * 256, m0 = blockIdx.y * 64, b = blockIdx.z;
    int gk = g * 320;
    int ty = tid >> 5, tx = tid & 31;    // 8 x 32
    float acc[8][8] = {};
    int wm = tid >> 2, wkk = (tid & 3) << 1;
    int xkk = tid >> 5, xn = (tid & 31) * 8;
    for (int k0 = 0; k0 < 320; k0 += 8) {
        __syncthreads();
        {
            const float* wsrc = &wf[(size_t)(m0 + wm) * 960 + gk + k0 + wkk];
            float2 w2 = *(const float2*)wsrc;
            Wt[wkk][wm] = w2.x;
            Wt[wkk + 1][wm] = w2.y;
            const float* xsrc = &slice[((size_t)(b * C5) + k0 + xkk) * CHWN + n0 + xn];
            float4 x0 = *(const float4*)xsrc;
            float4 x1 = *(const float4*)(xsrc + 4);
            *(float4*)&Xt[xkk][xn] = x0;
            *(float4*)&Xt[xkk][xn + 4] = x1;
        }
        __syncthreads();
        #pragma unroll
        for (int kk = 0; kk < 8; ++kk) {
            float4 a0 = *(const float4*)&Wt[kk][ty * 8];
            float4 a1 = *(const float4*)&Wt[kk][ty * 8 + 4];
            float4 b0 = *(const float4*)&Xt[kk][tx * 4];
            float4 b1 = *(const float4*)&Xt[kk][128 + tx * 4];
            float aa[8] = {a0.x, a0.y, a0.z, a0.w, a1.x, a1.y, a1.z, a1.w};
            float bb[8] = {b0.x, b0.y, b0.z, b0.w, b1.x, b1.y, b1.z, b1.w};
            #pragma unroll
            for (int i = 0; i < 8; ++i)
                #pragma unroll
                for (int j = 0; j < 8; ++j)
                    acc[i][j] = fmaf(aa[i], bb[j], acc[i][j]);
        }
    }
    #pragma unroll
    for (int i = 0; i < 8; ++i) {
        int m = m0 + ty * 8 + i;
        size_t base = ((size_t)(b * C5) + m) * HW + (size_t)r0 * IMW + n0;
        float* p0 = &qkv[base + tx * 4];
        float* p1 = &qkv[base + 128 + tx * 4];
        if (g == 0) {
            float bv = bias[m];
            float4 o0, o1;
            o0.x = acc[i][0] + bv; o0.y = acc[i][1] + bv; o0.z = acc[i][2] + bv; o0.w = acc[i][3] + bv;
            o1.x = acc[i][4] + bv; o1.y = acc[i][5] + bv; o1.z = acc[i][6] + bv; o1.w = acc[i][7] + bv;
            *(float4*)p0 = o0;
            *(float4*)p1 = o1;
        } else {
            float4 c0 = *(const float4*)p0;
            float4 c1 = *(const float4*)p1;
            c0.x += acc[i][0]; c0.y += acc[i][1]; c0.z += acc[i][2]; c0.w += acc[i][3];
            c1.x += acc[i][4]; c1.y += acc[i][5]; c1.z += acc[i][6]; c1.w += acc[i][7];
            *(float4*)p0 = c0;
            *(float4*)p1 = c1;
        }
    }
}

// ---------- K6a: build (value || index) u64 keys for v rows ----------
__global__ void k_build_keys(const float* __restrict__ qkv, uint64_t* __restrict__ keyA) {
    int j = blockIdx.x * 256 + threadIdx.x;
    int row = blockIdx.y;               // b*64+c
    int b = row >> 6, c = row & 63;
    float v = qkv[((size_t)(b * C5) + 256 + c) * HW + j];
    keyA[(size_t)row * HW + j] = (((uint64_t)f2s(v)) << 32) | (uint32_t)j;
}

// ---------- K6b-1: per-(row,seg) 8-bit digit histogram (coalesced, order-free) ----------
__global__ __launch_bounds__(256) void k_rcount(const uint64_t* __restrict__ in, uint32_t* __restrict__ cntG,
                                                int shift) {
    __shared__ uint32_t hist[256];
    int t = threadIdx.x;
    int seg = blockIdx.x, row = blockIdx.y;
    hist[t] = 0;
    __syncthreads();
    const uint64_t* src = in + (size_t)row * HW + (size_t)seg * SEGN;
    #pragma unroll
    for (int i = 0; i < SEGN / 256; ++i) {
        unsigned d = (unsigned)(src[i * 256 + t] >> shift) & 255u;
        atomicAdd(&hist[d], 1u);
    }
    __syncthreads();
    cntG[((size_t)row * NSEG + seg) * 256 + t] = hist[t];
}

// ---------- K6b-2: per-row scan -> absolute dest base per (seg,digit), in place ----------
__global__ __launch_bounds__(256) void k_rscan(uint32_t* __restrict__ cntG) {
    __shared__ uint32_t tot[256];
    __shared__ uint32_t dbase[256];
    int d = threadIdx.x;
    int row = blockIdx.x;
    uint32_t* base = cntG + (size_t)row * NSEG * 256;
    uint32_t c[NSEG];
    uint32_t s = 0;
    #pragma unroll
    for (int sg = 0; sg < NSEG; ++sg) { c[sg] = base[sg * 256 + d]; s += c[sg]; }
    tot[d] = s;
    __syncthreads();
    if (d == 0) {
        uint32_t acc = 0;
        for (int i = 0; i < 256; ++i) { dbase[i] = acc; acc += tot[i]; }
    }
    __syncthreads();
    uint32_t run = dbase[d];
    #pragma unroll
    for (int sg = 0; sg < NSEG; ++sg) { uint32_t cv = c[sg]; base[sg * 256 + d] = run; run += cv; }
}

// ---------- K6b-3: stable scatter: ballot in-wave rank + cross-wave LDS prefix + running base ----------
__global__ __launch_bounds__(256) void k_rscatter(const uint64_t* __restrict__ in, uint64_t* __restrict__ out,
                                                  const uint32_t* __restrict__ cntG, int shift) {
    __shared__ uint16_t wcnt[4][256];
    __shared__ uint32_t runbase[256];
    int t = threadIdx.x;
    int w = t >> 6, lane = t & 63;
    int seg = blockIdx.x, row = blockIdx.y;
    runbase[t] = cntG[((size_t)row * NSEG + seg) * 256 + t];
    const uint64_t* src = in + (size_t)row * HW + (size_t)seg * SEGN;
    uint64_t* dst = out + (size_t)row * HW;
    for (int i = 0; i < SEGN / 256; ++i) {
        __syncthreads();
        ((uint64_t*)wcnt)[t] = 0;          // zero 4*256 u16
        __syncthreads();
        uint64_t k = src[i * 256 + t];
        unsigned d = (unsigned)(k >> shift) & 255u;
        // lanes in this wave with the same digit:
        uint64_t peers = ~0ull;
        #pragma unroll
        for (int bit = 0; bit < 8; ++bit) {
            uint64_t bm = __ballot((d >> bit) & 1u);
            peers &= ((d >> bit) & 1u) ? bm : ~bm;
        }
        unsigned lanerank = (unsigned)__popcll(peers & ((1ull << lane) - 1ull));
        unsigned wtotal = (unsigned)__popcll(peers);
        if (lanerank == 0) wcnt[w][d] = (uint16_t)wtotal;
        __syncthreads();
        unsigned wpre = 0;
        #pragma unroll
        for (int ww = 0; ww < 4; ++ww) {
            unsigned cv = wcnt[ww][d];
            if (ww < w) wpre += cv;
        }
        unsigned pos = runbase[d] + wpre + lanerank;
        dst[pos] = k;
        __syncthreads();
        runbase[t] += (uint32_t)wcnt[0][t] + wcnt[1][t] + wcnt[2][t] + wcnt[3][t];
    }
}

// ---------- K6c: unpack sorted keys -> vs, idxv ----------
__global__ void k_unpack(const uint64_t* __restrict__ keys, float* __restrict__ vs, int* __restrict__ idxv) {
    int j = blockIdx.x * 256 + threadIdx.x;
    int row = blockIdx.y;
    size_t o = (size_t)row * HW + j;
    uint64_t k = keys[o];
    vs[o] = s2f((uint32_t)(k >> 32));
    idxv[o] = (int)(k & 0xFFFFFFFFull);
}

// ---------- K6d: gather q1,k1,q2,k2 into sorted order; one channel phase at a time ----------
// resident set per block = one 144KB source row -> 16 blocks/XCD * 144KB = 2.3MB < 4MB L2
__global__ __launch_bounds__(1024) void k_gather4(const int* __restrict__ idxv, const float* __restrict__ qkv,
                                                  float* __restrict__ g4) {
    int row = blockIdx.x;                 // b*64 + cg
    int b = row >> 6, cg = row & 63;
    const int* irow = idxv + (size_t)row * HW;
    size_t S4 = (size_t)BB * CC * HW;     // 4718592
    for (int ph = 0; ph < 4; ++ph) {
        const float* src = qkv + ((size_t)(b * C5) + ph * 64 + cg) * HW;
        float* dst = g4 + (size_t)ph * S4 + (size_t)row * HW;
        for (int j = threadIdx.x; j < HW; j += 4096) {
            int p0 = irow[j];
            int p1 = irow[j + 1024];
            int p2 = irow[j + 2048];
            int p3 = irow[j + 3072];
            dst[j]        = src[p0];
            dst[j + 1024] = src[p1];
            dst[j + 2048] = src[p2];
            dst[j + 3072] = src[p3];
        }
        __syncthreads();
    }
}

// ---------- K7a: S partials + norm^2 partials, streaming from g4 ----------
__global__ __launch_bounds__(256) void k_attn_qk(const float* __restrict__ g4,
                                                 float* __restrict__ partS, float* __restrict__ partN) {
    __shared__ float Qs[16][68];
    __shared__ float Ks[16][68];
    __shared__ float nqs[4][64];
    __shared__ float nks[4][64];
    int tid = threadIdx.x;
    int ychunk = blockIdx.x;   // NCHUNK chunks of CHN
    int z = blockIdx.y;        // 16 = b(2) x h(4) x variant(2)
    int vi = z & 1, hh = (z >> 1) & 3, b = z >> 3;
    size_t S4 = (size_t)BB * CC * HW;
    const float* Q = g4 + (vi ? 2 * S4 : (size_t)0);
    const float* Kp = g4 + (vi ? 3 * S4 : S4);
    int ty = tid >> 4, tx = tid & 15;
    float acc[4][4] = {};
    float nq = 0.f, nk = 0.f;
    int d0 = tid & 63, kset = tid >> 6;
    int nbase0 = ychunk * CHN;
    for (int it = 0; it < CHN / 16; ++it) {
        int nb0 = nbase0 + it * 16;
        __syncthreads();
        #pragma unroll
        for (int l = 0; l < 4; ++l) {
            int idx = l * 256 + tid;
            int d = idx >> 4, kk = idx & 15;
            int n = nb0 + kk;
            int cch = hh * 16 + (d >> 2), f = d & 3;
            size_t off = ((size_t)(b * CC) + cch) * HW + (vi ? (size_t)(n * 4 + f) : (size_t)(f * NQ + n));
            Qs[kk][d] = Q[off];
            Ks[kk][d] = Kp[off];
        }
        __syncthreads();
        #pragma unroll
        for (int kk = 0; kk < 16; ++kk) {
            float4 av = *(const float4*)&Qs[kk][ty * 4];
            float4 bv = *(const float4*)&Ks[kk][tx * 4];
            float aa[4] = {av.x, av.y, av.z, av.w};
            float bb[4] = {bv.x, bv.y, bv.z, bv.w};
            #pragma unroll
            for (int i = 0; i < 4; ++i)
                #pragma unroll
                for (int j = 0; j < 4; ++j)
                    acc[i][j] = fmaf(aa[i], bb[j], acc[i][j]);
        }
        #pragma unroll
        for (int kk2 = 0; kk2 < 4; ++kk2) {
            float qv = Qs[kset * 4 + kk2][d0];
            float kv = Ks[kset * 4 + kk2][d0];
            nq = fmaf(qv, qv, nq);
            nk = fmaf(kv, kv, nk);
        }
    }
    size_t sb = ((size_t)z * NCHUNK + ychunk) * 4096;
    #pragma unroll
    for (int i = 0; i < 4; ++i)
        #pragma unroll
        for (int j = 0; j < 4; ++j)
            partS[sb + (size_t)(ty * 4 + i) * 64 + tx * 4 + j] = acc[i][j];
    nqs[kset][d0] = nq;
    nks[kset][d0] = nk;
    __syncthreads();
    if (tid < 64) {
        float sq = nqs[0][tid] + nqs[1][tid] + nqs[2][tid] + nqs[3][tid];
        float sk = nks[0][tid] + nks[1][tid] + nks[2][tid] + nks[3][tid];
        size_t nb2 = ((size_t)z * NCHUNK + ychunk) * 128;
        partN[nb2 + tid] = sq;
        partN[nb2 + 64 + tid] = sk;
    }
}

// ---------- K7b: reduce partials, normalize, exp, denom = rowsum+1 ; write attn^T ----------
__global__ __launch_bounds__(256) void k_attn_softmax(const float* __restrict__ partS,
                                                      const float* __restrict__ partN,
                                                      const float* __restrict__ temp, float* __restrict__ attnT) {
    __shared__ float nqv[64], nkv[64];
    __shared__ float pbuf[64][65];
    __shared__ float rred[64][4];
    __shared__ float rsum[64];
    int tid = threadIdx.x;
    int z = blockIdx.x;
    int hh = (z >> 1) & 3;
    if (tid < 128) {
        float s = 0.f;
        for (int ch = 0; ch < NCHUNK; ++ch) s += partN[((size_t)z * NCHUNK + ch) * 128 + tid];
        float nv = fmaxf(sqrtf(s), 1e-12f);
        if (tid < 64) nqv[tid] = nv; else nkv[tid - 64] = nv;
    }
    __syncthreads();
    float tf = temp[hh];
    int d = tid >> 2, qq = tid & 3;
    float psum = 0.f;
    for (int e = qq * 16; e < qq * 16 + 16; ++e) {
        float s = 0.f;
        for (int ch = 0; ch < NCHUNK; ++ch) s += partS[((size_t)z * NCHUNK + ch) * 4096 + (size_t)d * 64 + e];
        float p = expf(tf * s / (nqv[d] * nkv[e]));
        pbuf[d][e] = p;
        psum += p;
    }
    rred[d][qq] = psum;
    __syncthreads();
    if (tid < 64) rsum[tid] = rred[tid][0] + rred[tid][1] + rred[tid][2] + rred[tid][3] + 1.0f;
    __syncthreads();
    for (int e = qq * 16; e < qq * 16 + 16; ++e)
        attnT[(size_t)z * 4096 + (size_t)e * 64 + d] = pbuf[d][e] / rsum[d];
}

// ---------- K7c: O = attn * V, written back to (c, sorted-position) layout ----------
__global__ __launch_bounds__(256) void k_attn_av(const float* __restrict__ attnT, const float* __restrict__ vs,
                                                 float* __restrict__ O1, float* __restrict__ O2) {
    __shared__ float at_s[4096];
    int tid = threadIdx.x;
    int z = blockIdx.y;
    int vi = z & 1, hh = (z >> 1) & 3, b = z >> 3;
    for (int l = 0; l < 16; ++l) at_s[l * 256 + tid] = attnT[(size_t)z * 4096 + l * 256 + tid];
    __syncthreads();
    int n = blockIdx.x * 256 + tid;
    float acc[64];
    #pragma unroll
    for (int d = 0; d < 64; ++d) acc[d] = 0.f;
    for (int e = 0; e < 64; ++e) {
        int cch = hh * 16 + (e >> 2), f = e & 3;
        size_t p = vi ? (size_t)(n * 4 + f) : (size_t)(f * NQ + n);
        float vv = vs[((size_t)(b * CC) + cch) * HW + p];
        const float* ar = &at_s[e * 64];
        #pragma unroll
        for (int d4 = 0; d4 < 16; ++d4) {
            float4 a4 = *(const float4*)&ar[d4 * 4];
            acc[d4 * 4 + 0] = fmaf(a4.x, vv, acc[d4 * 4 + 0]);
            acc[d4 * 4 + 1] = fmaf(a4.y, vv, acc[d4 * 4 + 1]);
            acc[d4 * 4 + 2] = fmaf(a4.z, vv, acc[d4 * 4 + 2]);
            acc[d4 * 4 + 3] = fmaf(a4.w, vv, acc[d4 * 4 + 3]);
        }
    }
    float* Ob = vi ? O2 : O1;
    #pragma unroll
    for (int d = 0; d < 64; ++d) {
        int cch = hh * 16 + (d >> 2), f = d & 3;
        size_t p = vi ? (size_t)(n * 4 + f) : (size_t)(f * NQ + n);
        Ob[((size_t)(b * CC) + cch) * HW + p] = acc[d];
    }
}

// ---------- K8: product in sorted domain, scatter to original positions via idxv ----------
__global__ void k_prod_scatter(const float* __restrict__ O1, const float* __restrict__ O2,
                               const int* __restrict__ idxv, float* __restrict__ pu) {
    int j = blockIdx.x * 256 + threadIdx.x;
    int row = blockIdx.y;
    size_t o = (size_t)row * HW + j;
    int p = idxv[o];
    pu[(size_t)row * HW + p] = O1[o] * O2[o];
}

// ---------- K9: proj GEMM 64x64 ----------
__global__ __launch_bounds__(256) void k_gemm_proj(const float* __restrict__ wp, const float* __restrict__ pu,
                                                   float* __restrict__ op) {
    __shared__ float wt[4096];  // wt[c*64+m] = wp[m*64+c]
    int tid = threadIdx.x;
    for (int l = 0; l < 16; ++l) {
        int i = l * 256 + tid;
        int m = i >> 6, c = i & 63;
        wt[c * 64 + m] = wp[i];
    }
    __syncthreads();
    int b = blockIdx.y;
    int n = blockIdx.x * 256 + tid;
    float acc[64];
    #pragma unroll
    for (int m = 0; m < 64; ++m) acc[m] = 0.f;
    const float* src = pu + (size_t)(b * CC) * HW + n;
    for (int c = 0; c < 64; ++c) {
        float xv = src[(size_t)c * HW];
        const float* wr = &wt[c * 64];
        #pragma unroll
        for (int m4 = 0; m4 < 16; ++m4) {
            float4 w4 = *(const float4*)&wr[m4 * 4];
            acc[m4 * 4 + 0] = fmaf(w4.x, xv, acc[m4 * 4 + 0]);
            acc[m4 * 4 + 1] = fmaf(w4.y, xv, acc[m4 * 4 + 1]);
            acc[m4 * 4 + 2] = fmaf(w4.z, xv, acc[m4 * 4 + 2]);
            acc[m4 * 4 + 3] = fmaf(w4.w, xv, acc[m4 * 4 + 3]);
        }
    }
    float* dst = op + (size_t)(b * CC) * HW + n;
    for (int m = 0; m < 64; ++m) dst[(size_t)m * HW] = acc[m];
}

// ---------- K10: spatial unsort scatter for c<32, copy c>=32 ----------
__global__ void k_final(const float* __restrict__ op, const int* __restrict__ idx_h,
                        const int* __restrict__ idx_w, float* __restrict__ out) {
    int i = blockIdx.x * 256 + threadIdx.x;
    int p = i % HW;
    int c = (i / HW) % CC;
    int b = i / (HW * CC);
    float v = op[i];
    if (c < CHF) {
        int h = p / IMW, w = p % IMW;
        size_t ib = ((size_t)(b * CHF) + c) * HW;
        int W0 = idx_w[ib + h * IMW + w];
        int H0 = idx_h[ib + h * IMW + W0];
        out[((size_t)(b * CC) + c) * HW + H0 * IMW + W0] = v;
    } else {
        out[i] = v;
    }
}

extern "C" void kernel_launch(void* const* d_in, const int* in_sizes, int n_in,
                              void* d_out, int out_size, void* d_ws, size_t ws_size,
                              hipStream_t stream) {
    (void)in_sizes; (void)n_in; (void)out_size; (void)ws_size;
    const float* x    = (const float*)d_in[0];
    const float* temp = (const float*)d_in[1];
    const float* wq   = (const float*)d_in[2];
    const float* wd3  = (const float*)d_in[3];
    const float* wd5  = (const float*)d_in[4];
    const float* wd7  = (const float*)d_in[5];
    const float* wf   = (const float*)d_in[6];
    const float* bf   = (const float*)d_in[7];
    const float* wp   = (const float*)d_in[8];
    float* out = (float*)d_out;
    float* ws = (float*)d_ws;

    // ---- workspace arena: peak 59,768,832 floats (~228 MiB) ----
    // R0: [0, 4718592)            idx_h + idx_w (int)                [live to end]
    // R1: [4718592, 12582912)     A / slice, then cntG (radix), then idxv
    // R2: [12582912, 36175872)    q, then keyA|keyB, then g4; vs @ [31457280,36175872)
    // R3: [36175872, 59768832)    qkv, then O1|O2|pu|op|partS|partN|attnT
    int*      idx_h = (int*)(ws + 0);
    int*      idx_w = (int*)(ws + 2359296);
    float*    A     = ws + 4718592;
    float*    slice = ws + 4718592;                    // over dead A
    float*    q     = ws + 12582912;
    float*    qkv   = ws + 36175872;
    uint64_t* keyA  = (uint64_t*)(ws + 12582912);      // over dead q
    uint64_t* keyB  = (uint64_t*)(ws + 22020096);
    float*    vs    = ws + 31457280;
    uint32_t* cntG  = (uint32_t*)(ws + 4718592);       // radix bases: 128*16*256 u32 (over dead slice)
    int*      idxv  = (int*)(ws + 4718592);            // after radix (over dead cntG)
    float*    g4    = ws + 12582912;                   // over dead keyA+keyB (exactly 18874368)
    float*    O1    = ws + 36175872;                   // over dead qkv
    float*    O2    = ws + 40894464;
    float*    pu    = ws + 45613056;
    float*    op    = ws + 50331648;                   // ends 55050240
    float*    partS = ws + 55050240;                   // 16*32*4096 = 2097152
    float*    partN = ws + 57147392;                   // 65536
    float*    attnT = ws + 57212928;                   // 65536 -> ends 57278464 < 59768832

    k_copy_back<<<9216, 256, 0, stream>>>(x, A);
    k_sort_h<<<12288, 128, 0, stream>>>(x, A, idx_h);
    k_sort_w<<<12288, 128, 0, stream>>>(A, idx_w);
    k_gemm_q<<<dim3(576, 5, 2), 256, 0, stream>>>(wq, A, q);

    for (int g = 0; g < 3; ++g) {
        for (int chunk = 0; chunk < 3; ++chunk) {
            int r0 = chunk * CROWS;
            if (g == 0)      k_dwconv<3><<<dim3(12, 320, 2), 256, 0, stream>>>(q, wd3, slice, r0);
            else if (g == 1) k_dwconv<5><<<dim3(12, 320, 2), 256, 0, stream>>>(q, wd5, slice, r0);
            else             k_dwconv<7><<<dim3(12, 320, 2), 256, 0, stream>>>(q, wd7, slice, r0);
            k_gemm_fuse<<<dim3(48, 5, 2), 256, 0, stream>>>(wf, slice, bf, qkv, g, r0);
        }
    }

    k_build_keys<<<dim3(144, 128), 256, 0, stream>>>(qkv, keyA);
    // 4 stable LSD passes of 8 bits over the value (bits 32..63); index bits are pre-sorted order
    const int shifts[4] = {32, 40, 48, 56};
    for (int p = 0; p < 4; ++p) {
        const uint64_t* src = (p & 1) ? keyB : keyA;
        uint64_t*       dst = (p & 1) ? keyA : keyB;
        k_rcount  <<<dim3(NSEG, 128), 256, 0, stream>>>(src, cntG, shifts[p]);
        k_rscan   <<<128, 256, 0, stream>>>(cntG);
        k_rscatter<<<dim3(NSEG, 128), 256, 0, stream>>>(src, dst, cntG, shifts[p]);
    }
    k_unpack<<<dim3(144, 128), 256, 0, stream>>>(keyA, vs, idxv);
    k_gather4<<<128, 1024, 0, stream>>>(idxv, qkv, g4);

    k_attn_qk<<<dim3(NCHUNK, 16), 256, 0, stream>>>(g4, partS, partN);
    k_attn_softmax<<<16, 256, 0, stream>>>(partS, partN, temp, attnT);
    k_attn_av<<<dim3(36, 16), 256, 0, stream>>>(attnT, vs, O1, O2);

    k_prod_scatter<<<dim3(144, 128), 256, 0, stream>>>(O1, O2, idxv, pu);
    k_gemm_proj<<<dim3(144, 2), 256, 0, stream>>>(wp, pu, op);
    k_final<<<18432, 256, 0, stream>>>(op, idx_h, idx_w, out);
}

// Round 5
// 1634.095 us; speedup vs baseline: 1.2455x; 1.0123x over previous
//
#include <hip/hip_runtime.h>
#include <stdint.h>
#include <stddef.h>

constexpr int IMH = 192;
constexpr int IMW = 192;
constexpr int HW  = 36864;   // 192*192
constexpr int BB  = 2;
constexpr int CC  = 64;
constexpr int CHF = 32;      // half channels (sorted part)
constexpr int C5  = 320;     // 5*CC
constexpr int NQ  = 9216;    // HW/4
constexpr int CROWS = 64;    // fuse-pipeline chunk rows
constexpr int CHWN  = CROWS * IMW;  // 12288 cols per chunk
constexpr int NCHUNK = 32;   // attn_qk n-chunks per z
constexpr int CHN = HW / 4 / NCHUNK;  // 288 n per chunk
constexpr int NSEG = 16;     // radix segments per row
constexpr int SEGN = HW / NSEG;      // 2304 elements per segment (= 9 * 256)

// ---------- float <-> monotone uint32 (order-preserving, invertible) ----------
static __device__ __forceinline__ uint32_t f2s(float f) {
    uint32_t u = __float_as_uint(f);
    return (u & 0x80000000u) ? ~u : (u | 0x80000000u);
}
static __device__ __forceinline__ float s2f(uint32_t s) {
    uint32_t u = (s & 0x80000000u) ? (s & 0x7FFFFFFFu) : ~s;
    return __uint_as_float(u);
}

// ---------- bitonic sort of 256 u64 keys in LDS (128 threads) ----------
static __device__ void bitonic256(uint64_t* keys, int tid) {
    for (unsigned k = 2; k <= 256; k <<= 1) {
        for (unsigned j = k >> 1; j; j >>= 1) {
            __syncthreads();
            unsigned i = ((tid & ~(j - 1)) << 1) | (tid & (j - 1));
            unsigned p = i | j;
            bool up = ((i & k) == 0);
            uint64_t a = keys[i], b = keys[p];
            if ((a > b) == up) { keys[i] = b; keys[p] = a; }
        }
    }
    __syncthreads();
}

// ---------- K0: copy unsorted half channels into A ----------
__global__ void k_copy_back(const float* __restrict__ x, float* __restrict__ A) {
    int i = blockIdx.x * 256 + threadIdx.x;        // over BB*CHF*HW
    int b = i / (CHF * HW);
    int r = i % (CHF * HW);
    size_t o = ((size_t)(b * CC) + CHF) * HW + r;
    A[o] = x[o];
}

// ---------- K1: stable sort along H (per b,c,w column), write A + idx_h ----------
__global__ __launch_bounds__(128) void k_sort_h(const float* __restrict__ x, float* __restrict__ A,
                                                int* __restrict__ idx_h) {
    __shared__ uint64_t keys[256];
    int tid = threadIdx.x;
    int blk = blockIdx.x;
    int w = blk % IMW;
    int c = (blk / IMW) % CHF;
    int b = blk / (IMW * CHF);
    const float* col = x + ((size_t)(b * CC) + c) * HW + w;
    for (int i = tid; i < 256; i += 128)
        keys[i] = (i < IMH) ? ((((uint64_t)f2s(col[(size_t)i * IMW])) << 32) | (uint32_t)i) : ~0ull;
    bitonic256(keys, tid);
    float* ocol = A + ((size_t)(b * CC) + c) * HW + w;
    int* icol = idx_h + ((size_t)(b * CHF) + c) * HW + w;
    for (int i = tid; i < IMH; i += 128) {
        uint64_t k = keys[i];
        ocol[(size_t)i * IMW] = s2f((uint32_t)(k >> 32));
        icol[(size_t)i * IMW] = (int)(k & 0xFFFFFFFFull);
    }
}

// ---------- K2: stable sort along W (per b,c,h row), in-place on A, write idx_w ----------
__global__ __launch_bounds__(128) void k_sort_w(float* __restrict__ A, int* __restrict__ idx_w) {
    __shared__ uint64_t keys[256];
    int tid = threadIdx.x;
    int blk = blockIdx.x;
    int h = blk % IMH;
    int c = (blk / IMH) % CHF;
    int b = blk / (IMH * CHF);
    float* row = A + ((size_t)(b * CC) + c) * HW + (size_t)h * IMW;
    for (int i = tid; i < 256; i += 128)
        keys[i] = (i < IMW) ? ((((uint64_t)f2s(row[i])) << 32) | (uint32_t)i) : ~0ull;
    bitonic256(keys, tid);
    int* irow = idx_w + ((size_t)(b * CHF) + c) * HW + (size_t)h * IMW;
    for (int i = tid; i < IMW; i += 128) {
        uint64_t k = keys[i];
        row[i] = s2f((uint32_t)(k >> 32));
        irow[i] = (int)(k & 0xFFFFFFFFull);
    }
}

// ---------- K3: q = W_qkv(320x64) * A(64xHW) per batch ----------
__global__ __launch_bounds__(256) void k_gemm_q(const float* __restrict__ wq, const float* __restrict__ A,
                                                float* __restrict__ q) {
    __shared__ float Wt[64][68];
    __shared__ float Xt[64][68];
    int tid = threadIdx.x;
    int n0 = blockIdx.x * 64, m0 = blockIdx.y * 64, b = blockIdx.z;
    for (int l = 0; l < 16; ++l) {
        int idx = l * 256 + tid;
        int cc = idx & 63, m = idx >> 6;
        Wt[cc][m] = wq[(size_t)(m0 + m) * 64 + cc];
    }
    for (int l = 0; l < 16; ++l) {
        int idx = l * 256 + tid;
        int n = idx & 63, cc = idx >> 6;
        Xt[cc][n] = A[((size_t)(b * CC) + cc) * HW + n0 + n];
    }
    __syncthreads();
    int ty = tid >> 4, tx = tid & 15;
    float acc[4][4] = {};
    for (int cc = 0; cc < 64; ++cc) {
        float4 av = *(const float4*)&Wt[cc][ty * 4];
        float4 bv = *(const float4*)&Xt[cc][tx * 4];
        float aa[4] = {av.x, av.y, av.z, av.w};
        float bb[4] = {bv.x, bv.y, bv.z, bv.w};
        #pragma unroll
        for (int i = 0; i < 4; ++i)
            #pragma unroll
            for (int j = 0; j < 4; ++j)
                acc[i][j] = fmaf(aa[i], bb[j], acc[i][j]);
    }
    for (int i = 0; i < 4; ++i) {
        float4 o;
        o.x = acc[i][0]; o.y = acc[i][1]; o.z = acc[i][2]; o.w = acc[i][3];
        *(float4*)&q[((size_t)(b * C5) + m0 + ty * 4 + i) * HW + n0 + tx * 4] = o;
    }
}

// ---------- K4: depthwise conv KSxKS (zero pad) for a 64-row chunk starting at r0 ----------
template <int KS>
__global__ __launch_bounds__(256) void k_dwconv(const float* __restrict__ q, const float* __restrict__ wd,
                                                float* __restrict__ slice, int r0) {
    constexpr int PAD = KS / 2;
    constexpr int EXT = 32 + 2 * PAD;
    __shared__ float tile[EXT][EXT];
    int tid = threadIdx.x;
    int b = blockIdx.z, c = blockIdx.y;
    int t = blockIdx.x;                  // 12 tiles: 2 tile-rows x 6 tile-cols
    int ty0 = r0 + (t / 6) * 32, tx0 = (t % 6) * 32;
    const float* src = q + ((size_t)(b * C5) + c) * HW;
    for (int i = tid; i < EXT * EXT; i += 256) {
        int iy = i / EXT, ix = i % EXT;
        int gy = ty0 + iy - PAD, gx = tx0 + ix - PAD;
        float v = 0.f;
        if (gy >= 0 && gy < IMH && gx >= 0 && gx < IMW) v = src[gy * IMW + gx];
        tile[iy][ix] = v;
    }
    __syncthreads();
    float wreg[KS * KS];
    #pragma unroll
    for (int i = 0; i < KS * KS; ++i) wreg[i] = wd[(size_t)c * KS * KS + i];
    float* dst = slice + ((size_t)(b * C5) + c) * CHWN;
    #pragma unroll
    for (int k = 0; k < 4; ++k) {
        int pix = k * 256 + tid;
        int py = pix >> 5, px = pix & 31;
        float acc = 0.f;
        #pragma unroll
        for (int ky = 0; ky < KS; ++ky)
            #pragma unroll
            for (int kx = 0; kx < KS; ++kx)
                acc = fmaf(tile[py + ky][px + kx], wreg[ky * KS + kx], acc);
        dst[(ty0 - r0 + py) * IMW + tx0 + px] = acc;
    }
}

// ---------- K5: qkv(chunk) (+)= W_fuse[:, g*320:(g+1)*320] * slice(chunk) ----------
// 64x256 tile, 8x8 acc per thread, BK=16, full-float4 staging.
__global__ __launch_bounds__(256) void k_gemm_fuse(const float* __restrict__ wf, const float* __restrict__ slice,
                                                   const float* __restrict__ bias, float* __restrict__ qkv,
                                                   int g, int r0) {
    __shared__ float Wt[16][72];
    __shared__ float Xt[16][260];
    int tid = threadIdx.x;
    int n0 = blockIdx.x * 256, m0 = blockIdx.y * 64, b = blockIdx.z;
    int gk = g * 320;
    int ty = tid >> 5, tx = tid & 31;    // 8 x 32
    float acc[8][8] = {};
    int wm = tid >> 2, wkq = (tid & 3) << 2;             // W: m = tid>>2, 4 consecutive kk
    int xkk = tid >> 4, xn = (tid & 15) * 16;            // X: kk = tid>>4, 16 consecutive n
    for (int k0 = 0; k0 < 320; k0 += 16) {
        __syncthreads();
        {
            float4 w4 = *(const float4*)&wf[(size_t)(m0 + wm) * 960 + gk + k0 + wkq];
            Wt[wkq + 0][wm] = w4.x;
            Wt[wkq + 1][wm] = w4.y;
            Wt[wkq + 2][wm] = w4.z;
            Wt[wkq + 3][wm] = w4.w;
            const float* xsrc = &slice[((size_t)(b * C5) + k0 + xkk) * CHWN + n0 + xn];
            float4 x0 = *(const float4*)xsrc;
            float4 x1 = *(const float4*)(xsrc + 4);
            float4 x2 = *(const float4*)(xsrc + 8);
            float4 x3 = *(const float4*)(xsrc + 12);
            *(float4*)&Xt[xkk][xn] = x0;
            *(float4*)&Xt[xkk][xn + 4] = x1;
            *(float4*)&Xt[xkk][xn + 8] = x2;
            *(float4*)&Xt[xkk][xn + 12] = x3;
        }
        __syncthreads();
        #pragma unroll
        for (int kk = 0; kk < 16; ++kk) {
            float4 a0 = *(const float4*)&Wt[kk][ty * 8];
            float4 a1 = *(const float4*)&Wt[kk][ty * 8 + 4];
            float4 b0 = *(const float4*)&Xt[kk][tx * 4];
            float4 b1 = *(const float4*)&Xt[kk][128 + tx * 4];
            float aa[8] = {a0.x, a0.y, a0.z, a0.w, a1.x, a1.y, a1.z, a1.w};
            float bb[8] = {b0.x, b0.y, b0.z, b0.w, b1.x, b1.y, b1.z, b1.w};
            #pragma unroll
            for (int i = 0; i < 8; ++i)
                #pragma unroll
                for (int j = 0; j < 8; ++j)
                    acc[i][j] = fmaf(aa[i], bb[j], acc[i][j]);
        }
    }
    #pragma unroll
    for (int i = 0; i < 8; ++i) {
        int m = m0 + ty * 8 + i;
        size_t base = ((size_t)(b * C5) + m) * HW + (size_t)r0 * IMW + n0;
        float* p0 = &qkv[base + tx * 4];
        float* p1 = &qkv[base + 128 + tx * 4];
        if (g == 0) {
            float bv = bias[m];
            float4 o0, o1;
            o0.x = acc[i][0] + bv; o0.y = acc[i][1] + bv; o0.z = acc[i][2] + bv; o0.w = acc[i][3] + bv;
            o1.x = acc[i][4] + bv; o1.y = acc[i][5] + bv; o1.z = acc[i][6] + bv; o1.w = acc[i][7] + bv;
            *(float4*)p0 = o0;
            *(float4*)p1 = o1;
        } else {
            float4 c0 = *(const float4*)p0;
            float4 c1 = *(const float4*)p1;
            c0.x += acc[i][0]; c0.y += acc[i][1]; c0.z += acc[i][2]; c0.w += acc[i][3];
            c1.x += acc[i][4]; c1.y += acc[i][5]; c1.z += acc[i][6]; c1.w += acc[i][7];
            *(float4*)p0 = c0;
            *(float4*)p1 = c1;
        }
    }
}

// ---------- K6a: build (value || index) u64 keys for v rows ----------
__global__ void k_build_keys(const float* __restrict__ qkv, uint64_t* __restrict__ keyA) {
    int j = blockIdx.x * 256 + threadIdx.x;
    int row = blockIdx.y;               // b*64+c
    int b = row >> 6, c = row & 63;
    float v = qkv[((size_t)(b * C5) + 256 + c) * HW + j];
    keyA[(size_t)row * HW + j] = (((uint64_t)f2s(v)) << 32) | (uint32_t)j;
}

// ---------- K6b-1: per-(row,seg) 8-bit digit histogram (coalesced, order-free) ----------
__global__ __launch_bounds__(256) void k_rcount(const uint64_t* __restrict__ in, uint32_t* __restrict__ cntG,
                                                int shift) {
    __shared__ uint32_t hist[256];
    int t = threadIdx.x;
    int seg = blockIdx.x, row = blockIdx.y;
    hist[t] = 0;
    __syncthreads();
    const uint64_t* src = in + (size_t)row * HW + (size_t)seg * SEGN;
    #pragma unroll
    for (int i = 0; i < SEGN / 256; ++i) {
        unsigned d = (unsigned)(src[i * 256 + t] >> shift) & 255u;
        atomicAdd(&hist[d], 1u);
    }
    __syncthreads();
    cntG[((size_t)row * NSEG + seg) * 256 + t] = hist[t];
}

// ---------- K6b-2: per-row scan -> absolute dest base per (seg,digit), in place ----------
__global__ __launch_bounds__(256) void k_rscan(uint32_t* __restrict__ cntG) {
    __shared__ uint32_t tot[256];
    __shared__ uint32_t dbase[256];
    int d = threadIdx.x;
    int row = blockIdx.x;
    uint32_t* base = cntG + (size_t)row * NSEG * 256;
    uint32_t c[NSEG];
    uint32_t s = 0;
    #pragma unroll
    for (int sg = 0; sg < NSEG; ++sg) { c[sg] = base[sg * 256 + d]; s += c[sg]; }
    tot[d] = s;
    __syncthreads();
    if (d == 0) {
        uint32_t acc = 0;
        for (int i = 0; i < 256; ++i) { dbase[i] = acc; acc += tot[i]; }
    }
    __syncthreads();
    uint32_t run = dbase[d];
    #pragma unroll
    for (int sg = 0; sg < NSEG; ++sg) { uint32_t cv = c[sg]; base[sg * 256 + d] = run; run += cv; }
}

// ---------- K6b-3: stable scatter: ballot in-wave rank + cross-wave LDS prefix + running base ----------
__global__ __launch_bounds__(256) void k_rscatter(const uint64_t* __restrict__ in, uint64_t* __restrict__ out,
                                                  const uint32_t* __restrict__ cntG, int shift) {
    __shared__ uint16_t wcnt[4][256];
    __shared__ uint32_t runbase[256];
    int t = threadIdx.x;
    int w = t >> 6, lane = t & 63;
    int seg = blockIdx.x, row = blockIdx.y;
    runbase[t] = cntG[((size_t)row * NSEG + seg) * 256 + t];
    const uint64_t* src = in + (size_t)row * HW + (size_t)seg * SEGN;
    uint64_t* dst = out + (size_t)row * HW;
    for (int i = 0; i < SEGN / 256; ++i) {
        __syncthreads();
        ((uint64_t*)wcnt)[t] = 0;          // zero 4*256 u16
        __syncthreads();
        uint64_t k = src[i * 256 + t];
        unsigned d = (unsigned)(k >> shift) & 255u;
        // lanes in this wave with the same digit:
        uint64_t peers = ~0ull;
        #pragma unroll
        for (int bit = 0; bit < 8; ++bit) {
            uint64_t bm = __ballot((d >> bit) & 1u);
            peers &= ((d >> bit) & 1u) ? bm : ~bm;
        }
        unsigned lanerank = (unsigned)__popcll(peers & ((1ull << lane) - 1ull));
        unsigned wtotal = (unsigned)__popcll(peers);
        if (lanerank == 0) wcnt[w][d] = (uint16_t)wtotal;
        __syncthreads();
        unsigned wpre = 0;
        #pragma unroll
        for (int ww = 0; ww < 4; ++ww) {
            unsigned cv = wcnt[ww][d];
            if (ww < w) wpre += cv;
        }
        unsigned pos = runbase[d] + wpre + lanerank;
        dst[pos] = k;
        __syncthreads();
        runbase[t] += (uint32_t)wcnt[0][t] + wcnt[1][t] + wcnt[2][t] + wcnt[3][t];
    }
}

// ---------- K6c: unpack sorted keys -> vs, idxv ----------
__global__ void k_unpack(const uint64_t* __restrict__ keys, float* __restrict__ vs, int* __restrict__ idxv) {
    int j = blockIdx.x * 256 + threadIdx.x;
    int row = blockIdx.y;
    size_t o = (size_t)row * HW + j;
    uint64_t k = keys[o];
    vs[o] = s2f((uint32_t)(k >> 32));
    idxv[o] = (int)(k & 0xFFFFFFFFull);
}

// ---------- K6d: gather one channel-phase per block into sorted order ----------
// grid (128 rows, 4 phases), rows-fastest dispatch: concurrent blocks hold distinct
// 144KB src rows -> L2-local; 512 blocks x 8 waves = full occupancy on 256 CUs.
__global__ __launch_bounds__(512) void k_gather4(const int* __restrict__ idxv, const float* __restrict__ qkv,
                                                 float* __restrict__ g4) {
    int row = blockIdx.x;                 // b*64 + cg
    int ph = blockIdx.y;
    int b = row >> 6, cg = row & 63;
    const int* irow = idxv + (size_t)row * HW;
    size_t S4 = (size_t)BB * CC * HW;     // 4718592
    const float* src = qkv + ((size_t)(b * C5) + ph * 64 + cg) * HW;
    float* dst = g4 + (size_t)ph * S4 + (size_t)row * HW;
    int tid = threadIdx.x;
    for (int j = tid; j < HW; j += 2048) {
        int p0 = irow[j];
        int p1 = irow[j + 512];
        int p2 = irow[j + 1024];
        int p3 = irow[j + 1536];
        dst[j]        = src[p0];
        dst[j + 512]  = src[p1];
        dst[j + 1024] = src[p2];
        dst[j + 1536] = src[p3];
    }
}

// ---------- K7a: S partials + norm^2 partials, streaming from g4 ----------
__global__ __launch_bounds__(256) void k_attn_qk(const float* __restrict__ g4,
                                                 float* __restrict__ partS, float* __restrict__ partN) {
    __shared__ float Qs[16][68];
    __shared__ float Ks[16][68];
    __shared__ float nqs[4][64];
    __shared__ float nks[4][64];
    int tid = threadIdx.x;
    int ychunk = blockIdx.x;   // NCHUNK chunks of CHN
    int z = blockIdx.y;        // 16 = b(2) x h(4) x variant(2)
    int vi = z & 1, hh = (z >> 1) & 3, b = z >> 3;
    size_t S4 = (size_t)BB * CC * HW;
    const float* Q = g4 + (vi ? 2 * S4 : (size_t)0);
    const float* Kp = g4 + (vi ? 3 * S4 : S4);
    int ty = tid >> 4, tx = tid & 15;
    float acc[4][4] = {};
    float nq = 0.f, nk = 0.f;
    int d0 = tid & 63, kset = tid >> 6;
    int nbase0 = ychunk * CHN;
    for (int it = 0; it < CHN / 16; ++it) {
        int nb0 = nbase0 + it * 16;
        __syncthreads();
        #pragma unroll
        for (int l = 0; l < 4; ++l) {
            int idx = l * 256 + tid;
            int d = idx >> 4, kk = idx & 15;
            int n = nb0 + kk;
            int cch = hh * 16 + (d >> 2), f = d & 3;
            size_t off = ((size_t)(b * CC) + cch) * HW + (vi ? (size_t)(n * 4 + f) : (size_t)(f * NQ + n));
            Qs[kk][d] = Q[off];
            Ks[kk][d] = Kp[off];
        }
        __syncthreads();
        #pragma unroll
        for (int kk = 0; kk < 16; ++kk) {
            float4 av = *(const float4*)&Qs[kk][ty * 4];
            float4 bv = *(const float4*)&Ks[kk][tx * 4];
            float aa[4] = {av.x, av.y, av.z, av.w};
            float bb[4] = {bv.x, bv.y, bv.z, bv.w};
            #pragma unroll
            for (int i = 0; i < 4; ++i)
                #pragma unroll
                for (int j = 0; j < 4; ++j)
                    acc[i][j] = fmaf(aa[i], bb[j], acc[i][j]);
        }
        #pragma unroll
        for (int kk2 = 0; kk2 < 4; ++kk2) {
            float qv = Qs[kset * 4 + kk2][d0];
            float kv = Ks[kset * 4 + kk2][d0];
            nq = fmaf(qv, qv, nq);
            nk = fmaf(kv, kv, nk);
        }
    }
    size_t sb = ((size_t)z * NCHUNK + ychunk) * 4096;
    #pragma unroll
    for (int i = 0; i < 4; ++i)
        #pragma unroll
        for (int j = 0; j < 4; ++j)
            partS[sb + (size_t)(ty * 4 + i) * 64 + tx * 4 + j] = acc[i][j];
    nqs[kset][d0] = nq;
    nks[kset][d0] = nk;
    __syncthreads();
    if (tid < 64) {
        float sq = nqs[0][tid] + nqs[1][tid] + nqs[2][tid] + nqs[3][tid];
        float sk = nks[0][tid] + nks[1][tid] + nks[2][tid] + nks[3][tid];
        size_t nb2 = ((size_t)z * NCHUNK + ychunk) * 128;
        partN[nb2 + tid] = sq;
        partN[nb2 + 64 + tid] = sk;
    }
}

// ---------- K7b: reduce partials, normalize, exp, denom = rowsum+1 ; write attn^T ----------
__global__ __launch_bounds__(256) void k_attn_softmax(const float* __restrict__ partS,
                                                      const float* __restrict__ partN,
                                                      const float* __restrict__ temp, float* __restrict__ attnT) {
    __shared__ float nqv[64], nkv[64];
    __shared__ float pbuf[64][65];
    __shared__ float rred[64][4];
    __shared__ float rsum[64];
    int tid = threadIdx.x;
    int z = blockIdx.x;
    int hh = (z >> 1) & 3;
    if (tid < 128) {
        float s = 0.f;
        for (int ch = 0; ch < NCHUNK; ++ch) s += partN[((size_t)z * NCHUNK + ch) * 128 + tid];
        float nv = fmaxf(sqrtf(s), 1e-12f);
        if (tid < 64) nqv[tid] = nv; else nkv[tid - 64] = nv;
    }
    __syncthreads();
    float tf = temp[hh];
    int d = tid >> 2, qq = tid & 3;
    float psum = 0.f;
    for (int e = qq * 16; e < qq * 16 + 16; ++e) {
        float s = 0.f;
        for (int ch = 0; ch < NCHUNK; ++ch) s += partS[((size_t)z * NCHUNK + ch) * 4096 + (size_t)d * 64 + e];
        float p = expf(tf * s / (nqv[d] * nkv[e]));
        pbuf[d][e] = p;
        psum += p;
    }
    rred[d][qq] = psum;
    __syncthreads();
    if (tid < 64) rsum[tid] = rred[tid][0] + rred[tid][1] + rred[tid][2] + rred[tid][3] + 1.0f;
    __syncthreads();
    for (int e = qq * 16; e < qq * 16 + 16; ++e)
        attnT[(size_t)z * 4096 + (size_t)e * 64 + d] = pbuf[d][e] / rsum[d];
}

// ---------- K7c: O = attn * V, written back to (c, sorted-position) layout ----------
__global__ __launch_bounds__(256) void k_attn_av(const float* __restrict__ attnT, const float* __restrict__ vs,
                                                 float* __restrict__ O1, float* __restrict__ O2) {
    __shared__ float at_s[4096];
    int tid = threadIdx.x;
    int z = blockIdx.y;
    int vi = z & 1, hh = (z >> 1) & 3, b = z >> 3;
    for (int l = 0; l < 16; ++l) at_s[l * 256 + tid] = attnT[(size_t)z * 4096 + l * 256 + tid];
    __syncthreads();
    int n = blockIdx.x * 256 + tid;
    float acc[64];
    #pragma unroll
    for (int d = 0; d < 64; ++d) acc[d] = 0.f;
    for (int e = 0; e < 64; ++e) {
        int cch = hh * 16 + (e >> 2), f = e & 3;
        size_t p = vi ? (size_t)(n * 4 + f) : (size_t)(f * NQ + n);
        float vv = vs[((size_t)(b * CC) + cch) * HW + p];
        const float* ar = &at_s[e * 64];
        #pragma unroll
        for (int d4 = 0; d4 < 16; ++d4) {
            float4 a4 = *(const float4*)&ar[d4 * 4];
            acc[d4 * 4 + 0] = fmaf(a4.x, vv, acc[d4 * 4 + 0]);
            acc[d4 * 4 + 1] = fmaf(a4.y, vv, acc[d4 * 4 + 1]);
            acc[d4 * 4 + 2] = fmaf(a4.z, vv, acc[d4 * 4 + 2]);
            acc[d4 * 4 + 3] = fmaf(a4.w, vv, acc[d4 * 4 + 3]);
        }
    }
    float* Ob = vi ? O2 : O1;
    #pragma unroll
    for (int d = 0; d < 64; ++d) {
        int cch = hh * 16 + (d >> 2), f = d & 3;
        size_t p = vi ? (size_t)(n * 4 + f) : (size_t)(f * NQ + n);
        Ob[((size_t)(b * CC) + cch) * HW + p] = acc[d];
    }
}

// ---------- K8: product in sorted domain, scatter to original positions via idxv ----------
__global__ void k_prod_scatter(const float* __restrict__ O1, const float* __restrict__ O2,
                               const int* __restrict__ idxv, float* __restrict__ pu) {
    int j = blockIdx.x * 256 + threadIdx.x;
    int row = blockIdx.y;
    size_t o = (size_t)row * HW + j;
    int p = idxv[o];
    pu[(size_t)row * HW + p] = O1[o] * O2[o];
}

// ---------- K9: proj GEMM 64x64 ----------
__global__ __launch_bounds__(256) void k_gemm_proj(const float* __restrict__ wp, const float* __restrict__ pu,
                                                   float* __restrict__ op) {
    __shared__ float wt[4096];  // wt[c*64+m] = wp[m*64+c]
    int tid = threadIdx.x;
    for (int l = 0; l < 16; ++l) {
        int i = l * 256 + tid;
        int m = i >> 6, c = i & 63;
        wt[c * 64 + m] = wp[i];
    }
    __syncthreads();
    int b = blockIdx.y;
    int n = blockIdx.x * 256 + tid;
    float acc[64];
    #pragma unroll
    for (int m = 0; m < 64; ++m) acc[m] = 0.f;
    const float* src = pu + (size_t)(b * CC) * HW + n;
    for (int c = 0; c < 64; ++c) {
        float xv = src[(size_t)c * HW];
        const float* wr = &wt[c * 64];
        #pragma unroll
        for (int m4 = 0; m4 < 16; ++m4) {
            float4 w4 = *(const float4*)&wr[m4 * 4];
            acc[m4 * 4 + 0] = fmaf(w4.x, xv, acc[m4 * 4 + 0]);
            acc[m4 * 4 + 1] = fmaf(w4.y, xv, acc[m4 * 4 + 1]);
            acc[m4 * 4 + 2] = fmaf(w4.z, xv, acc[m4 * 4 + 2]);
            acc[m4 * 4 + 3] = fmaf(w4.w, xv, acc[m4 * 4 + 3]);
        }
    }
    float* dst = op + (size_t)(b * CC) * HW + n;
    for (int m = 0; m < 64; ++m) dst[(size_t)m * HW] = acc[m];
}

// ---------- K10: spatial unsort scatter for c<32, copy c>=32 ----------
__global__ void k_final(const float* __restrict__ op, const int* __restrict__ idx_h,
                        const int* __restrict__ idx_w, float* __restrict__ out) {
    int i = blockIdx.x * 256 + threadIdx.x;
    int p = i % HW;
    int c = (i / HW) % CC;
    int b = i / (HW * CC);
    float v = op[i];
    if (c < CHF) {
        int h = p / IMW, w = p % IMW;
        size_t ib = ((size_t)(b * CHF) + c) * HW;
        int W0 = idx_w[ib + h * IMW + w];
        int H0 = idx_h[ib + h * IMW + W0];
        out[((size_t)(b * CC) + c) * HW + H0 * IMW + W0] = v;
    } else {
        out[i] = v;
    }
}

extern "C" void kernel_launch(void* const* d_in, const int* in_sizes, int n_in,
                              void* d_out, int out_size, void* d_ws, size_t ws_size,
                              hipStream_t stream) {
    (void)in_sizes; (void)n_in; (void)out_size; (void)ws_size;
    const float* x    = (const float*)d_in[0];
    const float* temp = (const float*)d_in[1];
    const float* wq   = (const float*)d_in[2];
    const float* wd3  = (const float*)d_in[3];
    const float* wd5  = (const float*)d_in[4];
    const float* wd7  = (const float*)d_in[5];
    const float* wf   = (const float*)d_in[6];
    const float* bf   = (const float*)d_in[7];
    const float* wp   = (const float*)d_in[8];
    float* out = (float*)d_out;
    float* ws = (float*)d_ws;

    // ---- workspace arena: peak 59,768,832 floats (~228 MiB) ----
    int*      idx_h = (int*)(ws + 0);
    int*      idx_w = (int*)(ws + 2359296);
    float*    A     = ws + 4718592;
    float*    slice = ws + 4718592;                    // over dead A
    float*    q     = ws + 12582912;
    float*    qkv   = ws + 36175872;
    uint64_t* keyA  = (uint64_t*)(ws + 12582912);      // over dead q
    uint64_t* keyB  = (uint64_t*)(ws + 22020096);
    float*    vs    = ws + 31457280;
    uint32_t* cntG  = (uint32_t*)(ws + 4718592);       // radix bases (over dead slice)
    int*      idxv  = (int*)(ws + 4718592);            // after radix (over dead cntG)
    float*    g4    = ws + 12582912;                   // over dead keyA+keyB
    float*    O1    = ws + 36175872;                   // over dead qkv
    float*    O2    = ws + 40894464;
    float*    pu    = ws + 45613056;
    float*    op    = ws + 50331648;                   // ends 55050240
    float*    partS = ws + 55050240;                   // 2097152
    float*    partN = ws + 57147392;                   // 65536
    float*    attnT = ws + 57212928;                   // 65536 -> ends 57278464

    k_copy_back<<<9216, 256, 0, stream>>>(x, A);
    k_sort_h<<<12288, 128, 0, stream>>>(x, A, idx_h);
    k_sort_w<<<12288, 128, 0, stream>>>(A, idx_w);
    k_gemm_q<<<dim3(576, 5, 2), 256, 0, stream>>>(wq, A, q);

    for (int g = 0; g < 3; ++g) {
        for (int chunk = 0; chunk < 3; ++chunk) {
            int r0 = chunk * CROWS;
            if (g == 0)      k_dwconv<3><<<dim3(12, 320, 2), 256, 0, stream>>>(q, wd3, slice, r0);
            else if (g == 1) k_dwconv<5><<<dim3(12, 320, 2), 256, 0, stream>>>(q, wd5, slice, r0);
            else             k_dwconv<7><<<dim3(12, 320, 2), 256, 0, stream>>>(q, wd7, slice, r0);
            k_gemm_fuse<<<dim3(48, 5, 2), 256, 0, stream>>>(wf, slice, bf, qkv, g, r0);
        }
    }

    k_build_keys<<<dim3(144, 128), 256, 0, stream>>>(qkv, keyA);
    const int shifts[4] = {32, 40, 48, 56};
    for (int p = 0; p < 4; ++p) {
        const uint64_t* src = (p & 1) ? keyB : keyA;
        uint64_t*       dst = (p & 1) ? keyA : keyB;
        k_rcount  <<<dim3(NSEG, 128), 256, 0, stream>>>(src, cntG, shifts[p]);
        k_rscan   <<<128, 256, 0, stream>>>(cntG);
        k_rscatter<<<dim3(NSEG, 128), 256, 0, stream>>>(src, dst, cntG, shifts[p]);
    }
    k_unpack<<<dim3(144, 128), 256, 0, stream>>>(keyA, vs, idxv);
    k_gather4<<<dim3(128, 4), 512, 0, stream>>>(idxv, qkv, g4);

    k_attn_qk<<<dim3(NCHUNK, 16), 256, 0, stream>>>(g4, partS, partN);
    k_attn_softmax<<<16, 256, 0, stream>>>(partS, partN, temp, attnT);
    k_attn_av<<<dim3(36, 16), 256, 0, stream>>>(attnT, vs, O1, O2);

    k_prod_scatter<<<dim3(144, 128), 256, 0, stream>>>(O1, O2, idxv, pu);
    k_gemm_proj<<<dim3(144, 2), 256, 0, stream>>>(wp, pu, op);
    k_final<<<18432, 256, 0, stream>>>(op, idx_h, idx_w, out);
}

// Round 6
// 1615.114 us; speedup vs baseline: 1.2601x; 1.0118x over previous
//
#include <hip/hip_runtime.h>
#include <stdint.h>
#include <stddef.h>

constexpr int IMH = 192;
constexpr int IMW = 192;
constexpr int HW  = 36864;   // 192*192
constexpr int BB  = 2;
constexpr int CC  = 64;
constexpr int CHF = 32;      // half channels (sorted part)
constexpr int C5  = 320;     // 5*CC
constexpr int NQ  = 9216;    // HW/4
constexpr int CROWS = 64;    // fuse-pipeline chunk rows
constexpr int CHWN  = CROWS * IMW;  // 12288 cols per chunk
constexpr int NCHUNK = 32;   // attn_qk n-chunks per z
constexpr int CHN = HW / 4 / NCHUNK;  // 288 n per chunk
constexpr int NSEG = 16;     // radix segments per row
constexpr int SEGN = HW / NSEG;      // 2304 elements per segment (= 9 * 256)
constexpr int NBIN = 2048;   // 11-bit radix

// ---------- float <-> monotone uint32 (order-preserving, invertible) ----------
static __device__ __forceinline__ uint32_t f2s(float f) {
    uint32_t u = __float_as_uint(f);
    return (u & 0x80000000u) ? ~u : (u | 0x80000000u);
}
static __device__ __forceinline__ float s2f(uint32_t s) {
    uint32_t u = (s & 0x80000000u) ? (s & 0x7FFFFFFFu) : ~s;
    return __uint_as_float(u);
}

// ---------- bitonic sort of 256 u64 keys in LDS (128 threads) ----------
static __device__ void bitonic256(uint64_t* keys, int tid) {
    for (unsigned k = 2; k <= 256; k <<= 1) {
        for (unsigned j = k >> 1; j; j >>= 1) {
            __syncthreads();
            unsigned i = ((tid & ~(j - 1)) << 1) | (tid & (j - 1));
            unsigned p = i | j;
            bool up = ((i & k) == 0);
            uint64_t a = keys[i], b = keys[p];
            if ((a > b) == up) { keys[i] = b; keys[p] = a; }
        }
    }
    __syncthreads();
}

// ---------- K0: copy unsorted half channels into A ----------
__global__ void k_copy_back(const float* __restrict__ x, float* __restrict__ A) {
    int i = blockIdx.x * 256 + threadIdx.x;        // over BB*CHF*HW
    int b = i / (CHF * HW);
    int r = i % (CHF * HW);
    size_t o = ((size_t)(b * CC) + CHF) * HW + r;
    A[o] = x[o];
}

// ---------- K1: stable sort along H (per b,c,w column), write A + idx_h ----------
__global__ __launch_bounds__(128) void k_sort_h(const float* __restrict__ x, float* __restrict__ A,
                                                int* __restrict__ idx_h) {
    __shared__ uint64_t keys[256];
    int tid = threadIdx.x;
    int blk = blockIdx.x;
    int w = blk % IMW;
    int c = (blk / IMW) % CHF;
    int b = blk / (IMW * CHF);
    const float* col = x + ((size_t)(b * CC) + c) * HW + w;
    for (int i = tid; i < 256; i += 128)
        keys[i] = (i < IMH) ? ((((uint64_t)f2s(col[(size_t)i * IMW])) << 32) | (uint32_t)i) : ~0ull;
    bitonic256(keys, tid);
    float* ocol = A + ((size_t)(b * CC) + c) * HW + w;
    int* icol = idx_h + ((size_t)(b * CHF) + c) * HW + w;
    for (int i = tid; i < IMH; i += 128) {
        uint64_t k = keys[i];
        ocol[(size_t)i * IMW] = s2f((uint32_t)(k >> 32));
        icol[(size_t)i * IMW] = (int)(k & 0xFFFFFFFFull);
    }
}

// ---------- K2: stable sort along W (per b,c,h row), in-place on A, write idx_w ----------
__global__ __launch_bounds__(128) void k_sort_w(float* __restrict__ A, int* __restrict__ idx_w) {
    __shared__ uint64_t keys[256];
    int tid = threadIdx.x;
    int blk = blockIdx.x;
    int h = blk % IMH;
    int c = (blk / IMH) % CHF;
    int b = blk / (IMH * CHF);
    float* row = A + ((size_t)(b * CC) + c) * HW + (size_t)h * IMW;
    for (int i = tid; i < 256; i += 128)
        keys[i] = (i < IMW) ? ((((uint64_t)f2s(row[i])) << 32) | (uint32_t)i) : ~0ull;
    bitonic256(keys, tid);
    int* irow = idx_w + ((size_t)(b * CHF) + c) * HW + (size_t)h * IMW;
    for (int i = tid; i < IMW; i += 128) {
        uint64_t k = keys[i];
        row[i] = s2f((uint32_t)(k >> 32));
        irow[i] = (int)(k & 0xFFFFFFFFull);
    }
}

// ---------- K3: q = W_qkv(320x64) * A(64xHW) per batch ----------
__global__ __launch_bounds__(256) void k_gemm_q(const float* __restrict__ wq, const float* __restrict__ A,
                                                float* __restrict__ q) {
    __shared__ float Wt[64][68];
    __shared__ float Xt[64][68];
    int tid = threadIdx.x;
    int n0 = blockIdx.x * 64, m0 = blockIdx.y * 64, b = blockIdx.z;
    for (int l = 0; l < 16; ++l) {
        int idx = l * 256 + tid;
        int cc = idx & 63, m = idx >> 6;
        Wt[cc][m] = wq[(size_t)(m0 + m) * 64 + cc];
    }
    for (int l = 0; l < 16; ++l) {
        int idx = l * 256 + tid;
        int n = idx & 63, cc = idx >> 6;
        Xt[cc][n] = A[((size_t)(b * CC) + cc) * HW + n0 + n];
    }
    __syncthreads();
    int ty = tid >> 4, tx = tid & 15;
    float acc[4][4] = {};
    for (int cc = 0; cc < 64; ++cc) {
        float4 av = *(const float4*)&Wt[cc][ty * 4];
        float4 bv = *(const float4*)&Xt[cc][tx * 4];
        float aa[4] = {av.x, av.y, av.z, av.w};
        float bb[4] = {bv.x, bv.y, bv.z, bv.w};
        #pragma unroll
        for (int i = 0; i < 4; ++i)
            #pragma unroll
            for (int j = 0; j < 4; ++j)
                acc[i][j] = fmaf(aa[i], bb[j], acc[i][j]);
    }
    for (int i = 0; i < 4; ++i) {
        float4 o;
        o.x = acc[i][0]; o.y = acc[i][1]; o.z = acc[i][2]; o.w = acc[i][3];
        *(float4*)&q[((size_t)(b * C5) + m0 + ty * 4 + i) * HW + n0 + tx * 4] = o;
    }
}

// ---------- K4: depthwise conv KSxKS (zero pad) for a 64-row chunk starting at r0 ----------
template <int KS>
__global__ __launch_bounds__(256) void k_dwconv(const float* __restrict__ q, const float* __restrict__ wd,
                                                float* __restrict__ slice, int r0) {
    constexpr int PAD = KS / 2;
    constexpr int EXT = 32 + 2 * PAD;
    __shared__ float tile[EXT][EXT];
    int tid = threadIdx.x;
    int b = blockIdx.z, c = blockIdx.y;
    int t = blockIdx.x;                  // 12 tiles: 2 tile-rows x 6 tile-cols
    int ty0 = r0 + (t / 6) * 32, tx0 = (t % 6) * 32;
    const float* src = q + ((size_t)(b * C5) + c) * HW;
    for (int i = tid; i < EXT * EXT; i += 256) {
        int iy = i / EXT, ix = i % EXT;
        int gy = ty0 + iy - PAD, gx = tx0 + ix - PAD;
        float v = 0.f;
        if (gy >= 0 && gy < IMH && gx >= 0 && gx < IMW) v = src[gy * IMW + gx];
        tile[iy][ix] = v;
    }
    __syncthreads();
    float wreg[KS * KS];
    #pragma unroll
    for (int i = 0; i < KS * KS; ++i) wreg[i] = wd[(size_t)c * KS * KS + i];
    float* dst = slice + ((size_t)(b * C5) + c) * CHWN;
    #pragma unroll
    for (int k = 0; k < 4; ++k) {
        int pix = k * 256 + tid;
        int py = pix >> 5, px = pix & 31;
        float acc = 0.f;
        #pragma unroll
        for (int ky = 0; ky < KS; ++ky)
            #pragma unroll
            for (int kx = 0; kx < KS; ++kx)
                acc = fmaf(tile[py + ky][px + kx], wreg[ky * KS + kx], acc);
        dst[(ty0 - r0 + py) * IMW + tx0 + px] = acc;
    }
}

// ---------- K5: qkv(chunk) (+)= W_fuse[:, g*320:(g+1)*320] * slice(chunk) ----------
// 64x256 tile, 8x8 acc per thread, BK=16, full-float4 staging.
__global__ __launch_bounds__(256) void k_gemm_fuse(const float* __restrict__ wf, const float* __restrict__ slice,
                                                   const float* __restrict__ bias, float* __restrict__ qkv,
                                                   int g, int r0) {
    __shared__ float Wt[16][72];
    __shared__ float Xt[16][260];
    int tid = threadIdx.x;
    int n0 = blockIdx.x * 256, m0 = blockIdx.y * 64, b = blockIdx.z;
    int gk = g * 320;
    int ty = tid >> 5, tx = tid & 31;    // 8 x 32
    float acc[8][8] = {};
    int wm = tid >> 2, wkq = (tid & 3) << 2;             // W: m = tid>>2, 4 consecutive kk
    int xkk = tid >> 4, xn = (tid & 15) * 16;            // X: kk = tid>>4, 16 consecutive n
    for (int k0 = 0; k0 < 320; k0 += 16) {
        __syncthreads();
        {
            float4 w4 = *(const float4*)&wf[(size_t)(m0 + wm) * 960 + gk + k0 + wkq];
            Wt[wkq + 0][wm] = w4.x;
            Wt[wkq + 1][wm] = w4.y;
            Wt[wkq + 2][wm] = w4.z;
            Wt[wkq + 3][wm] = w4.w;
            const float* xsrc = &slice[((size_t)(b * C5) + k0 + xkk) * CHWN + n0 + xn];
            float4 x0 = *(const float4*)xsrc;
            float4 x1 = *(const float4*)(xsrc + 4);
            float4 x2 = *(const float4*)(xsrc + 8);
            float4 x3 = *(const float4*)(xsrc + 12);
            *(float4*)&Xt[xkk][xn] = x0;
            *(float4*)&Xt[xkk][xn + 4] = x1;
            *(float4*)&Xt[xkk][xn + 8] = x2;
            *(float4*)&Xt[xkk][xn + 12] = x3;
        }
        __syncthreads();
        #pragma unroll
        for (int kk = 0; kk < 16; ++kk) {
            float4 a0 = *(const float4*)&Wt[kk][ty * 8];
            float4 a1 = *(const float4*)&Wt[kk][ty * 8 + 4];
            float4 b0 = *(const float4*)&Xt[kk][tx * 4];
            float4 b1 = *(const float4*)&Xt[kk][128 + tx * 4];
            float aa[8] = {a0.x, a0.y, a0.z, a0.w, a1.x, a1.y, a1.z, a1.w};
            float bb[8] = {b0.x, b0.y, b0.z, b0.w, b1.x, b1.y, b1.z, b1.w};
            #pragma unroll
            for (int i = 0; i < 8; ++i)
                #pragma unroll
                for (int j = 0; j < 8; ++j)
                    acc[i][j] = fmaf(aa[i], bb[j], acc[i][j]);
        }
    }
    #pragma unroll
    for (int i = 0; i < 8; ++i) {
        int m = m0 + ty * 8 + i;
        size_t base = ((size_t)(b * C5) + m) * HW + (size_t)r0 * IMW + n0;
        float* p0 = &qkv[base + tx * 4];
        float* p1 = &qkv[base + 128 + tx * 4];
        if (g == 0) {
            float bv = bias[m];
            float4 o0, o1;
            o0.x = acc[i][0] + bv; o0.y = acc[i][1] + bv; o0.z = acc[i][2] + bv; o0.w = acc[i][3] + bv;
            o1.x = acc[i][4] + bv; o1.y = acc[i][5] + bv; o1.z = acc[i][6] + bv; o1.w = acc[i][7] + bv;
            *(float4*)p0 = o0;
            *(float4*)p1 = o1;
        } else {
            float4 c0 = *(const float4*)p0;
            float4 c1 = *(const float4*)p1;
            c0.x += acc[i][0]; c0.y += acc[i][1]; c0.z += acc[i][2]; c0.w += acc[i][3];
            c1.x += acc[i][4]; c1.y += acc[i][5]; c1.z += acc[i][6]; c1.w += acc[i][7];
            *(float4*)p0 = c0;
            *(float4*)p1 = c1;
        }
    }
}

// ---------- K6a: build (value || index) u64 keys for v rows ----------
__global__ void k_build_keys(const float* __restrict__ qkv, uint64_t* __restrict__ keyA) {
    int j = blockIdx.x * 256 + threadIdx.x;
    int row = blockIdx.y;               // b*64+c
    int b = row >> 6, c = row & 63;
    float v = qkv[((size_t)(b * C5) + 256 + c) * HW + j];
    keyA[(size_t)row * HW + j] = (((uint64_t)f2s(v)) << 32) | (uint32_t)j;
}

// ---------- K6b-1: per-(row,seg) 11-bit digit histogram ----------
__global__ __launch_bounds__(256) void k_rcount(const uint64_t* __restrict__ in, uint32_t* __restrict__ cntG,
                                                int shift) {
    __shared__ uint32_t hist[NBIN];
    int t = threadIdx.x;
    int seg = blockIdx.x, row = blockIdx.y;
    #pragma unroll
    for (int k = 0; k < NBIN / 256; ++k) hist[k * 256 + t] = 0;
    __syncthreads();
    const uint64_t* src = in + (size_t)row * HW + (size_t)seg * SEGN;
    #pragma unroll
    for (int i = 0; i < SEGN / 256; ++i) {
        unsigned d = (unsigned)(src[i * 256 + t] >> shift) & (NBIN - 1);
        atomicAdd(&hist[d], 1u);
    }
    __syncthreads();
    uint32_t* dstc = cntG + ((size_t)row * NSEG + seg) * NBIN;
    #pragma unroll
    for (int k = 0; k < NBIN / 256; ++k) dstc[k * 256 + t] = hist[k * 256 + t];
}

// ---------- K6b-2: per-row two-level scan -> absolute dest base per (seg,digit) ----------
__global__ __launch_bounds__(256) void k_rscan(uint32_t* __restrict__ cntG) {
    __shared__ uint32_t tot[NBIN];
    __shared__ uint32_t gsum[256];
    __shared__ uint32_t gbase[256];
    int t = threadIdx.x;
    int row = blockIdx.x;
    uint32_t* base = cntG + (size_t)row * NSEG * NBIN;
    uint32_t loc = 0;
    #pragma unroll
    for (int k = 0; k < NBIN / 256; ++k) {
        int bn = t * (NBIN / 256) + k;
        uint32_t s = 0;
        for (int sg = 0; sg < NSEG; ++sg) s += base[sg * NBIN + bn];
        tot[bn] = s;
        loc += s;
    }
    gsum[t] = loc;
    __syncthreads();
    if (t == 0) {
        uint32_t acc = 0;
        for (int i = 0; i < 256; ++i) { uint32_t v = gsum[i]; gbase[i] = acc; acc += v; }
    }
    __syncthreads();
    uint32_t run = gbase[t];
    #pragma unroll
    for (int k = 0; k < NBIN / 256; ++k) {
        int bn = t * (NBIN / 256) + k;
        uint32_t tv = tot[bn];
        uint32_t r2 = run;
        for (int sg = 0; sg < NSEG; ++sg) {
            uint32_t cv = base[sg * NBIN + bn];
            base[sg * NBIN + bn] = r2;
            r2 += cv;
        }
        run += tv;
    }
}

// ---------- K6b-3: stable scatter (11-bit): ballot rank + cross-wave prefix + running base ----------
__global__ __launch_bounds__(256) void k_rscatter(const uint64_t* __restrict__ in, uint64_t* __restrict__ out,
                                                  const uint32_t* __restrict__ cntG, int shift) {
    __shared__ uint16_t wcnt[4][NBIN];
    __shared__ uint32_t runbase[NBIN];
    int t = threadIdx.x;
    int w = t >> 6, lane = t & 63;
    int seg = blockIdx.x, row = blockIdx.y;
    const uint32_t* cbase = cntG + ((size_t)row * NSEG + seg) * NBIN;
    #pragma unroll
    for (int k = 0; k < NBIN / 256; ++k) runbase[k * 256 + t] = cbase[k * 256 + t];
    const uint64_t* src = in + (size_t)row * HW + (size_t)seg * SEGN;
    uint64_t* dst = out + (size_t)row * HW;
    for (int i = 0; i < SEGN / 256; ++i) {
        __syncthreads();
        #pragma unroll
        for (int k = 0; k < NBIN / 256; ++k)
            ((uint64_t*)wcnt)[k * 256 + t] = 0;      // zero 4*NBIN u16 = NBIN u64
        __syncthreads();
        uint64_t kv = src[i * 256 + t];
        unsigned d = (unsigned)(kv >> shift) & (NBIN - 1);
        uint64_t peers = ~0ull;
        #pragma unroll
        for (int bit = 0; bit < 11; ++bit) {
            uint64_t bm = __ballot((d >> bit) & 1u);
            peers &= ((d >> bit) & 1u) ? bm : ~bm;
        }
        unsigned lanerank = (unsigned)__popcll(peers & ((1ull << lane) - 1ull));
        unsigned wtotal = (unsigned)__popcll(peers);
        if (lanerank == 0) wcnt[w][d] = (uint16_t)wtotal;
        __syncthreads();
        unsigned wpre = 0;
        #pragma unroll
        for (int ww = 0; ww < 4; ++ww) {
            unsigned cv = wcnt[ww][d];
            if (ww < w) wpre += cv;
        }
        unsigned pos = runbase[d] + wpre + lanerank;
        dst[pos] = kv;
        __syncthreads();
        #pragma unroll
        for (int k = 0; k < NBIN / 256; ++k) {
            int bn = k * 256 + t;
            runbase[bn] += (uint32_t)wcnt[0][bn] + wcnt[1][bn] + wcnt[2][bn] + wcnt[3][bn];
        }
    }
}

// ---------- K6c: unpack sorted keys -> vs, idxv ----------
__global__ void k_unpack(const uint64_t* __restrict__ keys, float* __restrict__ vs, int* __restrict__ idxv) {
    int j = blockIdx.x * 256 + threadIdx.x;
    int row = blockIdx.y;
    size_t o = (size_t)row * HW + j;
    uint64_t k = keys[o];
    vs[o] = s2f((uint32_t)(k >> 32));
    idxv[o] = (int)(k & 0xFFFFFFFFull);
}

// ---------- K6d: gather q1,k1,q2,k2 into sorted order ----------
// 256 blocks x 1024 thr; block = (row, j-half) with XCD swizzle: both halves of a row
// and only 16 distinct rows per XCD -> per-XCD L2 working set 16 x 144KB = 2.3MB < 4MB.
// Phases serialized so only one src row is hot per block at a time.
__global__ __launch_bounds__(1024) void k_gather4(const int* __restrict__ idxv, const float* __restrict__ qkv,
                                                  float* __restrict__ g4) {
    int i = blockIdx.x;
    int row = (i & 7) * 16 + ((i >> 3) & 15);   // same-XCD blocks share a 16-row window
    int jh = i >> 7;                             // 0 or 1
    int b = row >> 6, cg = row & 63;
    const int* irow = idxv + (size_t)row * HW + jh * (HW / 2);
    size_t S4 = (size_t)BB * CC * HW;            // 4718592
    int tid = threadIdx.x;
    for (int ph = 0; ph < 4; ++ph) {
        const float* src = qkv + ((size_t)(b * C5) + ph * 64 + cg) * HW;
        float* dst = g4 + (size_t)ph * S4 + (size_t)row * HW + jh * (HW / 2);
        #pragma unroll 2
        for (int j = tid; j < HW / 2; j += 1024)
            dst[j] = src[irow[j]];
        __syncthreads();
    }
}

// ---------- K7a: S partials + norm^2 partials, streaming from g4 ----------
__global__ __launch_bounds__(256) void k_attn_qk(const float* __restrict__ g4,
                                                 float* __restrict__ partS, float* __restrict__ partN) {
    __shared__ float Qs[16][68];
    __shared__ float Ks[16][68];
    __shared__ float nqs[4][64];
    __shared__ float nks[4][64];
    int tid = threadIdx.x;
    int ychunk = blockIdx.x;   // NCHUNK chunks of CHN
    int z = blockIdx.y;        // 16 = b(2) x h(4) x variant(2)
    int vi = z & 1, hh = (z >> 1) & 3, b = z >> 3;
    size_t S4 = (size_t)BB * CC * HW;
    const float* Q = g4 + (vi ? 2 * S4 : (size_t)0);
    const float* Kp = g4 + (vi ? 3 * S4 : S4);
    int ty = tid >> 4, tx = tid & 15;
    float acc[4][4] = {};
    float nq = 0.f, nk = 0.f;
    int d0 = tid & 63, kset = tid >> 6;
    int nbase0 = ychunk * CHN;
    for (int it = 0; it < CHN / 16; ++it) {
        int nb0 = nbase0 + it * 16;
        __syncthreads();
        #pragma unroll
        for (int l = 0; l < 4; ++l) {
            int idx = l * 256 + tid;
            int d = idx >> 4, kk = idx & 15;
            int n = nb0 + kk;
            int cch = hh * 16 + (d >> 2), f = d & 3;
            size_t off = ((size_t)(b * CC) + cch) * HW + (vi ? (size_t)(n * 4 + f) : (size_t)(f * NQ + n));
            Qs[kk][d] = Q[off];
            Ks[kk][d] = Kp[off];
        }
        __syncthreads();
        #pragma unroll
        for (int kk = 0; kk < 16; ++kk) {
            float4 av = *(const float4*)&Qs[kk][ty * 4];
            float4 bv = *(const float4*)&Ks[kk][tx * 4];
            float aa[4] = {av.x, av.y, av.z, av.w};
            float bb[4] = {bv.x, bv.y, bv.z, bv.w};
            #pragma unroll
            for (int i = 0; i < 4; ++i)
                #pragma unroll
                for (int j = 0; j < 4; ++j)
                    acc[i][j] = fmaf(aa[i], bb[j], acc[i][j]);
        }
        #pragma unroll
        for (int kk2 = 0; kk2 < 4; ++kk2) {
            float qv = Qs[kset * 4 + kk2][d0];
            float kv = Ks[kset * 4 + kk2][d0];
            nq = fmaf(qv, qv, nq);
            nk = fmaf(kv, kv, nk);
        }
    }
    size_t sb = ((size_t)z * NCHUNK + ychunk) * 4096;
    #pragma unroll
    for (int i = 0; i < 4; ++i)
        #pragma unroll
        for (int j = 0; j < 4; ++j)
            partS[sb + (size_t)(ty * 4 + i) * 64 + tx * 4 + j] = acc[i][j];
    nqs[kset][d0] = nq;
    nks[kset][d0] = nk;
    __syncthreads();
    if (tid < 64) {
        float sq = nqs[0][tid] + nqs[1][tid] + nqs[2][tid] + nqs[3][tid];
        float sk = nks[0][tid] + nks[1][tid] + nks[2][tid] + nks[3][tid];
        size_t nb2 = ((size_t)z * NCHUNK + ychunk) * 128;
        partN[nb2 + tid] = sq;
        partN[nb2 + 64 + tid] = sk;
    }
}

// ---------- K7b: reduce partials, normalize, exp, denom = rowsum+1 ; write attn^T ----------
__global__ __launch_bounds__(256) void k_attn_softmax(const float* __restrict__ partS,
                                                      const float* __restrict__ partN,
                                                      const float* __restrict__ temp, float* __restrict__ attnT) {
    __shared__ float nqv[64], nkv[64];
    __shared__ float pbuf[64][65];
    __shared__ float rred[64][4];
    __shared__ float rsum[64];
    int tid = threadIdx.x;
    int z = blockIdx.x;
    int hh = (z >> 1) & 3;
    if (tid < 128) {
        float s = 0.f;
        for (int ch = 0; ch < NCHUNK; ++ch) s += partN[((size_t)z * NCHUNK + ch) * 128 + tid];
        float nv = fmaxf(sqrtf(s), 1e-12f);
        if (tid < 64) nqv[tid] = nv; else nkv[tid - 64] = nv;
    }
    __syncthreads();
    float tf = temp[hh];
    int d = tid >> 2, qq = tid & 3;
    float psum = 0.f;
    for (int e = qq * 16; e < qq * 16 + 16; ++e) {
        float s = 0.f;
        for (int ch = 0; ch < NCHUNK; ++ch) s += partS[((size_t)z * NCHUNK + ch) * 4096 + (size_t)d * 64 + e];
        float p = expf(tf * s / (nqv[d] * nkv[e]));
        pbuf[d][e] = p;
        psum += p;
    }
    rred[d][qq] = psum;
    __syncthreads();
    if (tid < 64) rsum[tid] = rred[tid][0] + rred[tid][1] + rred[tid][2] + rred[tid][3] + 1.0f;
    __syncthreads();
    for (int e = qq * 16; e < qq * 16 + 16; ++e)
        attnT[(size_t)z * 4096 + (size_t)e * 64 + d] = pbuf[d][e] / rsum[d];
}

// ---------- K7c: O = attn * V, written back to (c, sorted-position) layout ----------
__global__ __launch_bounds__(256) void k_attn_av(const float* __restrict__ attnT, const float* __restrict__ vs,
                                                 float* __restrict__ O1, float* __restrict__ O2) {
    __shared__ float at_s[4096];
    int tid = threadIdx.x;
    int z = blockIdx.y;
    int vi = z & 1, hh = (z >> 1) & 3, b = z >> 3;
    for (int l = 0; l < 16; ++l) at_s[l * 256 + tid] = attnT[(size_t)z * 4096 + l * 256 + tid];
    __syncthreads();
    int n = blockIdx.x * 256 + tid;
    float acc[64];
    #pragma unroll
    for (int d = 0; d < 64; ++d) acc[d] = 0.f;
    for (int e = 0; e < 64; ++e) {
        int cch = hh * 16 + (e >> 2), f = e & 3;
        size_t p = vi ? (size_t)(n * 4 + f) : (size_t)(f * NQ + n);
        float vv = vs[((size_t)(b * CC) + cch) * HW + p];
        const float* ar = &at_s[e * 64];
        #pragma unroll
        for (int d4 = 0; d4 < 16; ++d4) {
            float4 a4 = *(const float4*)&ar[d4 * 4];
            acc[d4 * 4 + 0] = fmaf(a4.x, vv, acc[d4 * 4 + 0]);
            acc[d4 * 4 + 1] = fmaf(a4.y, vv, acc[d4 * 4 + 1]);
            acc[d4 * 4 + 2] = fmaf(a4.z, vv, acc[d4 * 4 + 2]);
            acc[d4 * 4 + 3] = fmaf(a4.w, vv, acc[d4 * 4 + 3]);
        }
    }
    float* Ob = vi ? O2 : O1;
    #pragma unroll
    for (int d = 0; d < 64; ++d) {
        int cch = hh * 16 + (d >> 2), f = d & 3;
        size_t p = vi ? (size_t)(n * 4 + f) : (size_t)(f * NQ + n);
        Ob[((size_t)(b * CC) + cch) * HW + p] = acc[d];
    }
}

// ---------- K8: product in sorted domain, scatter to original positions via idxv ----------
__global__ void k_prod_scatter(const float* __restrict__ O1, const float* __restrict__ O2,
                               const int* __restrict__ idxv, float* __restrict__ pu) {
    int j = blockIdx.x * 256 + threadIdx.x;
    int row = blockIdx.y;
    size_t o = (size_t)row * HW + j;
    int p = idxv[o];
    pu[(size_t)row * HW + p] = O1[o] * O2[o];
}

// ---------- K9: proj GEMM 64x64 ----------
__global__ __launch_bounds__(256) void k_gemm_proj(const float* __restrict__ wp, const float* __restrict__ pu,
                                                   float* __restrict__ op) {
    __shared__ float wt[4096];  // wt[c*64+m] = wp[m*64+c]
    int tid = threadIdx.x;
    for (int l = 0; l < 16; ++l) {
        int i = l * 256 + tid;
        int m = i >> 6, c = i & 63;
        wt[c * 64 + m] = wp[i];
    }
    __syncthreads();
    int b = blockIdx.y;
    int n = blockIdx.x * 256 + tid;
    float acc[64];
    #pragma unroll
    for (int m = 0; m < 64; ++m) acc[m] = 0.f;
    const float* src = pu + (size_t)(b * CC) * HW + n;
    for (int c = 0; c < 64; ++c) {
        float xv = src[(size_t)c * HW];
        const float* wr = &wt[c * 64];
        #pragma unroll
        for (int m4 = 0; m4 < 16; ++m4) {
            float4 w4 = *(const float4*)&wr[m4 * 4];
            acc[m4 * 4 + 0] = fmaf(w4.x, xv, acc[m4 * 4 + 0]);
            acc[m4 * 4 + 1] = fmaf(w4.y, xv, acc[m4 * 4 + 1]);
            acc[m4 * 4 + 2] = fmaf(w4.z, xv, acc[m4 * 4 + 2]);
            acc[m4 * 4 + 3] = fmaf(w4.w, xv, acc[m4 * 4 + 3]);
        }
    }
    float* dst = op + (size_t)(b * CC) * HW + n;
    for (int m = 0; m < 64; ++m) dst[(size_t)m * HW] = acc[m];
}

// ---------- K10: spatial unsort scatter for c<32, copy c>=32 ----------
__global__ void k_final(const float* __restrict__ op, const int* __restrict__ idx_h,
                        const int* __restrict__ idx_w, float* __restrict__ out) {
    int i = blockIdx.x * 256 + threadIdx.x;
    int p = i % HW;
    int c = (i / HW) % CC;
    int b = i / (HW * CC);
    float v = op[i];
    if (c < CHF) {
        int h = p / IMW, w = p % IMW;
        size_t ib = ((size_t)(b * CHF) + c) * HW;
        int W0 = idx_w[ib + h * IMW + w];
        int H0 = idx_h[ib + h * IMW + W0];
        out[((size_t)(b * CC) + c) * HW + H0 * IMW + W0] = v;
    } else {
        out[i] = v;
    }
}

extern "C" void kernel_launch(void* const* d_in, const int* in_sizes, int n_in,
                              void* d_out, int out_size, void* d_ws, size_t ws_size,
                              hipStream_t stream) {
    (void)in_sizes; (void)n_in; (void)out_size; (void)ws_size;
    const float* x    = (const float*)d_in[0];
    const float* temp = (const float*)d_in[1];
    const float* wq   = (const float*)d_in[2];
    const float* wd3  = (const float*)d_in[3];
    const float* wd5  = (const float*)d_in[4];
    const float* wd7  = (const float*)d_in[5];
    const float* wf   = (const float*)d_in[6];
    const float* bf   = (const float*)d_in[7];
    const float* wp   = (const float*)d_in[8];
    float* out = (float*)d_out;
    float* ws = (float*)d_ws;

    // ---- workspace arena: peak 59,768,832 floats (~228 MiB) ----
    int*      idx_h = (int*)(ws + 0);
    int*      idx_w = (int*)(ws + 2359296);
    float*    A     = ws + 4718592;
    float*    slice = ws + 4718592;                    // over dead A
    float*    q     = ws + 12582912;
    float*    qkv   = ws + 36175872;
    uint64_t* keyA  = (uint64_t*)(ws + 12582912);      // over dead q
    uint64_t* keyB  = (uint64_t*)(ws + 22020096);
    float*    vs    = ws + 31457280;
    uint32_t* cntG  = (uint32_t*)(ws + 4718592);       // 128*16*2048 u32 = 4.19M floats (over dead slice)
    int*      idxv  = (int*)(ws + 4718592);            // after radix (over dead cntG)
    float*    g4    = ws + 12582912;                   // over dead keyA+keyB
    float*    O1    = ws + 36175872;                   // over dead qkv
    float*    O2    = ws + 40894464;
    float*    pu    = ws + 45613056;
    float*    op    = ws + 50331648;                   // ends 55050240
    float*    partS = ws + 55050240;                   // 2097152
    float*    partN = ws + 57147392;                   // 65536
    float*    attnT = ws + 57212928;                   // 65536 -> ends 57278464

    k_copy_back<<<9216, 256, 0, stream>>>(x, A);
    k_sort_h<<<12288, 128, 0, stream>>>(x, A, idx_h);
    k_sort_w<<<12288, 128, 0, stream>>>(A, idx_w);
    k_gemm_q<<<dim3(576, 5, 2), 256, 0, stream>>>(wq, A, q);

    for (int g = 0; g < 3; ++g) {
        for (int chunk = 0; chunk < 3; ++chunk) {
            int r0 = chunk * CROWS;
            if (g == 0)      k_dwconv<3><<<dim3(12, 320, 2), 256, 0, stream>>>(q, wd3, slice, r0);
            else if (g == 1) k_dwconv<5><<<dim3(12, 320, 2), 256, 0, stream>>>(q, wd5, slice, r0);
            else             k_dwconv<7><<<dim3(12, 320, 2), 256, 0, stream>>>(q, wd7, slice, r0);
            k_gemm_fuse<<<dim3(48, 5, 2), 256, 0, stream>>>(wf, slice, bf, qkv, g, r0);
        }
    }

    k_build_keys<<<dim3(144, 128), 256, 0, stream>>>(qkv, keyA);
    // 3 stable LSD passes of 11 bits over the value (bits 32..63); final result in keyB
    const int shifts[3] = {32, 43, 54};
    for (int p = 0; p < 3; ++p) {
        const uint64_t* src = (p & 1) ? keyB : keyA;
        uint64_t*       dst = (p & 1) ? keyA : keyB;
        k_rcount  <<<dim3(NSEG, 128), 256, 0, stream>>>(src, cntG, shifts[p]);
        k_rscan   <<<128, 256, 0, stream>>>(cntG);
        k_rscatter<<<dim3(NSEG, 128), 256, 0, stream>>>(src, dst, cntG, shifts[p]);
    }
    k_unpack<<<dim3(144, 128), 256, 0, stream>>>(keyB, vs, idxv);
    k_gather4<<<256, 1024, 0, stream>>>(idxv, qkv, g4);

    k_attn_qk<<<dim3(NCHUNK, 16), 256, 0, stream>>>(g4, partS, partN);
    k_attn_softmax<<<16, 256, 0, stream>>>(partS, partN, temp, attnT);
    k_attn_av<<<dim3(36, 16), 256, 0, stream>>>(attnT, vs, O1, O2);

    k_prod_scatter<<<dim3(144, 128), 256, 0, stream>>>(O1, O2, idxv, pu);
    k_gemm_proj<<<dim3(144, 2), 256, 0, stream>>>(wp, pu, op);
    k_final<<<18432, 256, 0, stream>>>(op, idx_h, idx_w, out);
}